// Round 11
// baseline (359.682 us; speedup 1.0000x reference)
//
#include <hip/hip_runtime.h>
#include <hip/hip_fp16.h>

#define N_NODES 100000
#define N_EDGES 1600000
#define NPART   8
#define PART_SZ (N_NODES / NPART)   // 12500 (agg node mapping)
#define CAP 48                      // bucket capacity; degree ~ Poisson(16), P(>=48) ~ 1e-9
#define BSH  10                     // nodes per fill bin = 1024 (node-exclusive block ownership)
#define NBIN 98                     // ceil(100000 / 1024)
#define SCAP2 4096                  // per-(bin,stripe) staging cap: mean 2048, sigma 45 -> +45 sigma
#define SSH2 12                     // log2(SCAP2)
#define EPB  2048                   // edges per build block

static __device__ __forceinline__ float lrelu(float z) { return z > 0.f ? z : 0.2f * z; }
static __device__ __forceinline__ int imin(int a, int b) { return a < b ? a : b; }

// pack two floats into one u32 of fp16 pair (h payload is fp16 since round-9)
static __device__ __forceinline__ unsigned pack2h(float a, float b) {
    return __builtin_bit_cast(unsigned, __floats2half2_rn(a, b));
}

// ---------------- phase A: single-pass edge binning at 1024-node granularity ----------------
// (round-15: validated — bucket phase now ~25 us total, fill write-amp gone)
__global__ __launch_bounds__(256) void bucket_build(const int* __restrict__ ei, int* __restrict__ tails,
                                                    unsigned* __restrict__ stage) {
    __shared__ int lcnt[NBIN];
    __shared__ int lbase[NBIN];
    int tid = threadIdx.x;
    if (tid < NBIN) lcnt[tid] = 0;
    __syncthreads();

    int stripe = blockIdx.x & 7;
    int e0 = blockIdx.x * EPB;
    int binv[EPB / 256];
    int slotv[EPB / 256];
    unsigned vv[EPB / 256];
#pragma unroll
    for (int k = 0; k < EPB / 256; ++k) {
        int t = e0 + k * 256 + tid;
        binv[k] = -1;
        if (t < N_EDGES) {
            int d = __builtin_nontemporal_load(ei + N_EDGES + t);
            int s = __builtin_nontemporal_load(ei + t);
            int b = d >> BSH;
            vv[k] = ((unsigned)(d & ((1 << BSH) - 1)) << 17) | (unsigned)s;  // dloc 10b | src 17b
            slotv[k] = atomicAdd(&lcnt[b], 1);
            binv[k] = b;
        }
    }
    __syncthreads();

    if (tid < NBIN) lbase[tid] = atomicAdd(&tails[stripe * 128 + tid], lcnt[tid]);
    __syncthreads();

#pragma unroll
    for (int k = 0; k < EPB / 256; ++k) {
        if (binv[k] >= 0) {
            int pos = lbase[binv[k]] + slotv[k];
            if (pos < SCAP2)
                stage[((((unsigned)binv[k] << 3) | (unsigned)stripe) << SSH2) + (unsigned)pos] = vv[k];
        }
    }
}

// ---------------- phase B: node-exclusive bucket assembly, LDS counters only ----------------
__global__ __launch_bounds__(1024) void bucket_fill(const int* __restrict__ tails, const unsigned* __restrict__ stage,
                                                    int* __restrict__ cnt, int* __restrict__ srcs) {
    __shared__ int lc[1 << BSH];
    int tid = threadIdx.x;
    int bin = blockIdx.x;
    int base = bin << BSH;
    int nn = N_NODES - base; if (nn > (1 << BSH)) nn = 1 << BSH;
    if (tid < nn) {
        lc[tid] = 1;                           // self-loop occupies slot 0
        srcs[(base + tid) * CAP] = base + tid;
    }
    __syncthreads();

    for (int st = 0; st < 8; ++st) {
        int len = tails[st * 128 + bin];
        if (len > SCAP2) len = SCAP2;
        const unsigned* sl = stage + ((((unsigned)bin << 3) | (unsigned)st) << SSH2);
        for (int i = tid; i < len; i += 1024) {
            unsigned v = __builtin_nontemporal_load(sl + i);
            int dloc = (int)(v >> 17);
            int s = (int)(v & 0x1FFFFu);
            int slot = atomicAdd(&lc[dloc], 1);
            if (slot < CAP) srcs[(base + dloc) * CAP + slot] = s;
        }
    }
    __syncthreads();
    if (tid < nn) cnt[base + tid] = lc[tid];   // agg clamps deg > CAP
}

// ---------------- fused GEMM + attention logits (2 rows/thread, k-chunked LDS) ----------------
// Round-21: rounds 8/10 both hit ~51 us at 22-23% VALU because the k-loop is LDS-PIPE
// bound: per k, 1 row x 16 cols costs 1 ds_read_b32 + 4 ds_read_b128 = ~54 cy of LDS
// pipe vs 32 cy VALU (m134 costs; per-CU demand ~160K cy vs 122K kernel). The W
// broadcast reads dominate — broadcast still pays full pipe time. Fix: 2 ROWS PER
// THREAD — the same 4 W b128 reads now feed 32 FMAs (64 cy VALU vs ~60 cy DS, pipes
// balanced). x staged in k-chunks of 32 (stride 33 -> conflict-free), W chunk 8 KB.
template <int IN, int OUT, int HEADS>
__global__ __launch_bounds__(256) void gemm_al(const float* __restrict__ x, const float* __restrict__ W,
                                               const float* __restrict__ asrc, const float* __restrict__ adst,
                                               unsigned short* __restrict__ h, float* __restrict__ als,
                                               float* __restrict__ ald) {
    constexpr int SPLIT = OUT / 16;            // col-slices (4 or 2)
    constexpr int GRP = 4 / SPLIT;             // row-groups of waves (1 or 2)
    constexpr int NPB = 128 * GRP;             // rows per block (128 or 256)
    constexpr int KCH = 32;                    // k-chunk
    constexpr int KST = KCH + 1;               // padded stride: 33 -> conflict-free
    __shared__ alignas(16) float sx[NPB * KST];
    __shared__ alignas(16) float sw[KCH * OUT];
    int t = threadIdx.x;
    long base = (long)blockIdx.x * NPB;

    int w = t >> 6, lane = t & 63;
    int s = __builtin_amdgcn_readfirstlane(w % SPLIT);
    int rg = __builtin_amdgcn_readfirstlane(w / SPLIT);
    int r0 = rg * 128 + lane;
    int r1 = r0 + 64;
    long n0 = base + r0, n1 = base + r1;

    float acc0[16], acc1[16];
#pragma unroll
    for (int j = 0; j < 16; ++j) { acc0[j] = 0.f; acc1[j] = 0.f; }

    for (int k0 = 0; k0 < IN; k0 += KCH) {
        __syncthreads();                       // prior chunk fully consumed
        // stage x chunk: NPB rows x KCH floats (float4 granularity, 8 f4/row)
        for (int e = t; e < NPB * (KCH / 4); e += 256) {
            int row = e >> 3, c4 = e & 7;
            long gr = base + row;
            if (gr >= N_NODES) gr = N_NODES - 1;
            float4 v = *reinterpret_cast<const float4*>(&x[gr * IN + k0 + c4 * 4]);
            float* d = &sx[row * KST + c4 * 4];
            d[0] = v.x; d[1] = v.y; d[2] = v.z; d[3] = v.w;
        }
        // stage W chunk: KCH x OUT floats, fully coalesced
        for (int e = t; e < KCH * OUT / 4; e += 256)
            reinterpret_cast<float4*>(sw)[e] =
                reinterpret_cast<const float4*>(W + (long)k0 * OUT)[e];
        __syncthreads();                       // chunk ready

        const float* swb = sw + s * 16;
#pragma unroll 8
        for (int k = 0; k < KCH; ++k) {
            float xv0 = sx[r0 * KST + k];
            float xv1 = sx[r1 * KST + k];
            const float* Wr = swb + k * OUT;
#pragma unroll
            for (int j = 0; j < 16; ++j) {
                float wv = Wr[j];
                acc0[j] = fmaf(xv0, wv, acc0[j]);
                acc1[j] = fmaf(xv1, wv, acc1[j]);
            }
        }
    }

    // h writes (fp16), both rows
    if (n0 < N_NODES) {
        unsigned u[8];
#pragma unroll
        for (int k = 0; k < 8; ++k) u[k] = pack2h(acc0[2 * k], acc0[2 * k + 1]);
        uint4* dst = reinterpret_cast<uint4*>(&h[n0 * OUT + s * 16]);
        dst[0] = make_uint4(u[0], u[1], u[2], u[3]);
        dst[1] = make_uint4(u[4], u[5], u[6], u[7]);
    }
    if (n1 < N_NODES) {
        unsigned u[8];
#pragma unroll
        for (int k = 0; k < 8; ++k) u[k] = pack2h(acc1[2 * k], acc1[2 * k + 1]);
        uint4* dst = reinterpret_cast<uint4*>(&h[n1 * OUT + s * 16]);
        dst[0] = make_uint4(u[0], u[1], u[2], u[3]);
        dst[1] = make_uint4(u[4], u[5], u[6], u[7]);
    }

    float ps0 = 0.f, pd0 = 0.f, ps1 = 0.f, pd1 = 0.f;
#pragma unroll
    for (int j = 0; j < 16; ++j) {
        float as = asrc[s * 16 + j], ad = adst[s * 16 + j];
        ps0 = fmaf(acc0[j], as, ps0); pd0 = fmaf(acc0[j], ad, pd0);
        ps1 = fmaf(acc1[j], as, ps1); pd1 = fmaf(acc1[j], ad, pd1);
    }
    if (HEADS == SPLIT) {                      // layers 1-2: slice s IS head s
        if (n0 < N_NODES) { als[n0 * HEADS + s] = ps0; ald[n0 * HEADS + s] = pd0; }
        if (n1 < N_NODES) { als[n1 * HEADS + s] = ps1; ald[n1 * HEADS + s] = pd1; }
    } else {                                   // layer 3: sum the SPLIT col-slices
        __syncthreads();
        sx[r0 * 2 + s] = ps0;            sx[r1 * 2 + s] = ps1;
        sx[NPB * 2 + r0 * 2 + s] = pd0;  sx[NPB * 2 + r1 * 2 + s] = pd1;
        __syncthreads();
        if (t < NPB) {
            long nn = base + t;
            if (nn < N_NODES) {
                als[nn] = sx[t * 2] + sx[t * 2 + 1];
                ald[nn] = sx[NPB * 2 + t * 2] + sx[NPB * 2 + t * 2 + 1];
            }
        }
    }
}

// XCD-aligned node mapping for agg: XCD k (blockIdx&7) processes dst range k.
static __device__ __forceinline__ int agg_node(int blk, int wid) {
    return (blk & 7) * PART_SZ + (blk >> 3) * 4 + wid;
}

// ---------------- aggregation, H=4 C=16, fp16 payload, uint4 lanes ----------------
// Round-18's branchless depth-4 prefetch validated (VGPR=24-28 = loads live across the
// fence; VALU 67-69%). fp16 payload since round-9.
__global__ __launch_bounds__(256, 8) void agg_h4(const int* __restrict__ cnt, const int* __restrict__ srcs,
                                                 const unsigned short* __restrict__ h, const float* __restrict__ als,
                                                 const float* __restrict__ ald, const float* __restrict__ bias,
                                                 float* __restrict__ g, int do_relu) {
    const uint4* hrow = reinterpret_cast<const uint4*>(h);   // 8 uint4 per 64-ch row
    int wid = threadIdx.x >> 6, lane = threadIdx.x & 63;
    int n = agg_node(blockIdx.x, wid);
    if (n >= N_NODES) return;
    int q = lane >> 3, cc = lane & 7;
    int hd = cc >> 1;
    float ad = ald[n * 4 + hd];
    int deg = cnt[n]; if (deg > CAP) deg = CAP;   // deg >= 1 (self-loop), wave-uniform
    int dm1 = deg - 1;
    int sl = srcs[n * CAP + imin(lane, dm1)];     // whole bucket, one coalesced load

    // addresses (shfl chain), then 8 independent loads, all before the fence
    int s0 = __shfl(sl, imin(0 * 8 + q, dm1));
    int s1 = __shfl(sl, imin(1 * 8 + q, dm1));
    int s2 = __shfl(sl, imin(2 * 8 + q, dm1));
    int s3 = __shfl(sl, imin(3 * 8 + q, dm1));
    float al0 = als[s0 * 4 + hd];
    float al1 = als[s1 * 4 + hd];
    float al2 = als[s2 * 4 + hd];
    float al3 = als[s3 * 4 + hd];
    uint4 hv0 = hrow[(long)s0 * 8 + cc];
    uint4 hv1 = hrow[(long)s1 * 8 + cc];
    uint4 hv2 = hrow[(long)s2 * 8 + cc];
    uint4 hv3 = hrow[(long)s3 * 8 + cc];
    __builtin_amdgcn_sched_barrier(0);

    float a0 = 0.f, a1 = 0.f, a2 = 0.f, a3 = 0.f, a4 = 0.f, a5 = 0.f, a6 = 0.f, a7 = 0.f;
    float den = 0.f;
#define ACCUM(AL, HV, T)                                                \
    {                                                                   \
        float w = ((T) * 8 + q) < deg ? __expf(lrelu((AL) + ad)) : 0.f; \
        den += w;                                                       \
        __half2 p0 = __builtin_bit_cast(__half2, (HV).x);               \
        __half2 p1 = __builtin_bit_cast(__half2, (HV).y);               \
        __half2 p2 = __builtin_bit_cast(__half2, (HV).z);               \
        __half2 p3 = __builtin_bit_cast(__half2, (HV).w);               \
        a0 = fmaf(w, (float)p0.x, a0); a1 = fmaf(w, (float)p0.y, a1);   \
        a2 = fmaf(w, (float)p1.x, a2); a3 = fmaf(w, (float)p1.y, a3);   \
        a4 = fmaf(w, (float)p2.x, a4); a5 = fmaf(w, (float)p2.y, a5);   \
        a6 = fmaf(w, (float)p3.x, a6); a7 = fmaf(w, (float)p3.y, a7);   \
    }
    ACCUM(al0, hv0, 0)
    ACCUM(al1, hv1, 1)
    ACCUM(al2, hv2, 2)
    ACCUM(al3, hv3, 3)

    if (__builtin_expect(deg > 32, 0)) {          // wave-uniform rare tail
        for (int e = 32; e < deg; e += 8) {
            int ee = e + q;
            int s = __shfl(sl, imin(ee, dm1));
            float al = als[s * 4 + hd];
            uint4 hv = hrow[(long)s * 8 + cc];
            float w = ee < deg ? __expf(lrelu(al + ad)) : 0.f;
            den += w;
            __half2 p0 = __builtin_bit_cast(__half2, hv.x);
            __half2 p1 = __builtin_bit_cast(__half2, hv.y);
            __half2 p2 = __builtin_bit_cast(__half2, hv.z);
            __half2 p3 = __builtin_bit_cast(__half2, hv.w);
            a0 = fmaf(w, (float)p0.x, a0); a1 = fmaf(w, (float)p0.y, a1);
            a2 = fmaf(w, (float)p1.x, a2); a3 = fmaf(w, (float)p1.y, a3);
            a4 = fmaf(w, (float)p2.x, a4); a5 = fmaf(w, (float)p2.y, a5);
            a6 = fmaf(w, (float)p3.x, a6); a7 = fmaf(w, (float)p3.y, a7);
        }
    }
#undef ACCUM

#pragma unroll
    for (int d = 8; d <= 32; d <<= 1) {
        a0 += __shfl_xor(a0, d); a1 += __shfl_xor(a1, d);
        a2 += __shfl_xor(a2, d); a3 += __shfl_xor(a3, d);
        a4 += __shfl_xor(a4, d); a5 += __shfl_xor(a5, d);
        a6 += __shfl_xor(a6, d); a7 += __shfl_xor(a7, d);
        den += __shfl_xor(den, d);
    }
    if (q == 0) {
        float4 b0 = *reinterpret_cast<const float4*>(&bias[cc * 8]);
        float4 b1 = *reinterpret_cast<const float4*>(&bias[cc * 8 + 4]);
        float inv = 1.f / den;
        float4 o0, o1;
        o0.x = fmaf(a0, inv, b0.x); o0.y = fmaf(a1, inv, b0.y);
        o0.z = fmaf(a2, inv, b0.z); o0.w = fmaf(a3, inv, b0.w);
        o1.x = fmaf(a4, inv, b1.x); o1.y = fmaf(a5, inv, b1.y);
        o1.z = fmaf(a6, inv, b1.z); o1.w = fmaf(a7, inv, b1.w);
        if (do_relu) {
            o0.x = fmaxf(o0.x, 0.f); o0.y = fmaxf(o0.y, 0.f);
            o0.z = fmaxf(o0.z, 0.f); o0.w = fmaxf(o0.w, 0.f);
            o1.x = fmaxf(o1.x, 0.f); o1.y = fmaxf(o1.y, 0.f);
            o1.w = fmaxf(o1.w, 0.f); o1.z = fmaxf(o1.z, 0.f);
        }
        *reinterpret_cast<float4*>(&g[(long)n * 64 + cc * 8]) = o0;
        *reinterpret_cast<float4*>(&g[(long)n * 64 + cc * 8 + 4]) = o1;
    }
}

// ---------------- aggregation, H=1 C=32, fp16 payload, uint4 lanes ----------------
// Branchless fixed-depth-2 prefetch (16-edge groups, covers deg<=32) + rare tail.
__global__ __launch_bounds__(256, 8) void agg_h1(const int* __restrict__ cnt, const int* __restrict__ srcs,
                                                 const unsigned short* __restrict__ h3, const float* __restrict__ als,
                                                 const float* __restrict__ ald, const float* __restrict__ bias,
                                                 float* __restrict__ out) {
    const uint4* hrow = reinterpret_cast<const uint4*>(h3);  // 4 uint4 per 32-ch row
    int wid = threadIdx.x >> 6, lane = threadIdx.x & 63;
    int n = agg_node(blockIdx.x, wid);
    if (n >= N_NODES) return;
    int q = lane >> 2, cc = lane & 3;
    float ad = ald[n];
    int deg = cnt[n]; if (deg > CAP) deg = CAP;
    int dm1 = deg - 1;
    int sl = srcs[n * CAP + imin(lane, dm1)];

    int s0 = __shfl(sl, imin(0 * 16 + q, dm1));
    int s1 = __shfl(sl, imin(1 * 16 + q, dm1));
    float al0 = als[s0];
    float al1 = als[s1];
    uint4 hv0 = hrow[(long)s0 * 4 + cc];
    uint4 hv1 = hrow[(long)s1 * 4 + cc];
    __builtin_amdgcn_sched_barrier(0);

    float a0 = 0.f, a1 = 0.f, a2 = 0.f, a3 = 0.f, a4 = 0.f, a5 = 0.f, a6 = 0.f, a7 = 0.f;
    float den = 0.f;
#define ACCUM1(AL, HV, T)                                                \
    {                                                                    \
        float w = ((T) * 16 + q) < deg ? __expf(lrelu((AL) + ad)) : 0.f; \
        den += w;                                                        \
        __half2 p0 = __builtin_bit_cast(__half2, (HV).x);                \
        __half2 p1 = __builtin_bit_cast(__half2, (HV).y);                \
        __half2 p2 = __builtin_bit_cast(__half2, (HV).z);                \
        __half2 p3 = __builtin_bit_cast(__half2, (HV).w);                \
        a0 = fmaf(w, (float)p0.x, a0); a1 = fmaf(w, (float)p0.y, a1);    \
        a2 = fmaf(w, (float)p1.x, a2); a3 = fmaf(w, (float)p1.y, a3);    \
        a4 = fmaf(w, (float)p2.x, a4); a5 = fmaf(w, (float)p2.y, a5);    \
        a6 = fmaf(w, (float)p3.x, a6); a7 = fmaf(w, (float)p3.y, a7);    \
    }
    ACCUM1(al0, hv0, 0)
    ACCUM1(al1, hv1, 1)

    if (__builtin_expect(deg > 32, 0)) {          // wave-uniform rare tail
        for (int e = 32; e < deg; e += 16) {
            int ee = e + q;
            int s = __shfl(sl, imin(ee, dm1));
            float al = als[s];
            uint4 hv = hrow[(long)s * 4 + cc];
            float w = ee < deg ? __expf(lrelu(al + ad)) : 0.f;
            den += w;
            __half2 p0 = __builtin_bit_cast(__half2, hv.x);
            __half2 p1 = __builtin_bit_cast(__half2, hv.y);
            __half2 p2 = __builtin_bit_cast(__half2, hv.z);
            __half2 p3 = __builtin_bit_cast(__half2, hv.w);
            a0 = fmaf(w, (float)p0.x, a0); a1 = fmaf(w, (float)p0.y, a1);
            a2 = fmaf(w, (float)p1.x, a2); a3 = fmaf(w, (float)p1.y, a3);
            a4 = fmaf(w, (float)p2.x, a4); a5 = fmaf(w, (float)p2.y, a5);
            a6 = fmaf(w, (float)p3.x, a6); a7 = fmaf(w, (float)p3.y, a7);
        }
    }
#undef ACCUM1

#pragma unroll
    for (int d = 4; d <= 32; d <<= 1) {
        a0 += __shfl_xor(a0, d); a1 += __shfl_xor(a1, d);
        a2 += __shfl_xor(a2, d); a3 += __shfl_xor(a3, d);
        a4 += __shfl_xor(a4, d); a5 += __shfl_xor(a5, d);
        a6 += __shfl_xor(a6, d); a7 += __shfl_xor(a7, d);
        den += __shfl_xor(den, d);
    }
    if (q == 0) {
        float4 b0 = *reinterpret_cast<const float4*>(&bias[cc * 8]);
        float4 b1 = *reinterpret_cast<const float4*>(&bias[cc * 8 + 4]);
        float inv = 1.f / den;
        float4 o0, o1;
        o0.x = fmaf(a0, inv, b0.x); o0.y = fmaf(a1, inv, b0.y);
        o0.z = fmaf(a2, inv, b0.z); o0.w = fmaf(a3, inv, b0.w);
        o1.x = fmaf(a4, inv, b1.x); o1.y = fmaf(a5, inv, b1.y);
        o1.z = fmaf(a6, inv, b1.z); o1.w = fmaf(a7, inv, b1.w);
        *reinterpret_cast<float4*>(&out[(long)n * 32 + cc * 8]) = o0;
        *reinterpret_cast<float4*>(&out[(long)n * 32 + cc * 8 + 4]) = o1;
    }
}

extern "C" void kernel_launch(void* const* d_in, const int* in_sizes, int n_in,
                              void* d_out, int out_size, void* d_ws, size_t ws_size,
                              hipStream_t stream) {
    (void)in_sizes; (void)n_in; (void)out_size; (void)ws_size;
    const float* x   = (const float*)d_in[0];
    const int*   ei  = (const int*)d_in[1];
    const float* W1  = (const float*)d_in[2];
    const float* as1 = (const float*)d_in[3];
    const float* ad1 = (const float*)d_in[4];
    const float* b1  = (const float*)d_in[5];
    const float* W2  = (const float*)d_in[6];
    const float* as2 = (const float*)d_in[7];
    const float* ad2 = (const float*)d_in[8];
    const float* b2  = (const float*)d_in[9];
    const float* W3  = (const float*)d_in[10];
    const float* as3 = (const float*)d_in[11];
    const float* ad3 = (const float*)d_in[12];
    const float* b3  = (const float*)d_in[13];
    float* out = (float*)d_out;

    char* w = (char*)d_ws;
    auto alloc = [&](size_t bytes) {
        void* p = (void*)w;
        w += (bytes + 255) & ~(size_t)255;
        return p;
    };
    int*            cnt   = (int*)alloc((size_t)N_NODES * 4);
    int*            tails = (int*)alloc((size_t)1024 * 4);            // 8 stripes x 128-int pad
    int*            srcs  = (int*)alloc((size_t)N_NODES * CAP * 4);   // 19.2 MB
    unsigned short* h     = (unsigned short*)alloc((size_t)N_NODES * 64 * 2);  // fp16, 12.8 MB
    float*          g     = (float*)alloc((size_t)N_NODES * 64 * 4);  // 25.6 MB
    float*          als   = (float*)alloc((size_t)N_NODES * 4 * 4);
    float*          ald   = (float*)alloc((size_t)N_NODES * 4 * 4);
    // staging (12.85 MB) aliases g: consumed by bucket_fill before agg_h4 first writes g.
    unsigned*       stage = (unsigned*)g;

    hipMemsetAsync(tails, 0, (size_t)1024 * 4, stream);   // cnt memset no longer needed

    int g128 = (N_NODES + 127) / 128;  // 782  (layers 1-2: NPB=128)
    int g256 = (N_NODES + 255) / 256;  // 391  (layer 3:   NPB=256)
    int gAgg = ((N_NODES + 3) / 4 + 7) & ~7;   // 25000 -> mult of 8
    int gBuild = (N_EDGES + EPB - 1) / EPB;    // 782 (self-loops not staged)

    bucket_build<<<gBuild, 256, 0, stream>>>(ei, tails, stage);
    bucket_fill<<<NBIN, 1024, 0, stream>>>(tails, stage, cnt, srcs);

    // layer 1: x[100000,128] @ W1[128,64], H=4
    gemm_al<128, 64, 4><<<g128, 256, 0, stream>>>(x, W1, as1, ad1, h, als, ald);
    agg_h4<<<gAgg, 256, 0, stream>>>(cnt, srcs, h, als, ald, b1, g, 1);
    // layer 2: g[100000,64] @ W2[64,64], H=4
    gemm_al<64, 64, 4><<<g128, 256, 0, stream>>>(g, W2, as2, ad2, h, als, ald);
    agg_h4<<<gAgg, 256, 0, stream>>>(cnt, srcs, h, als, ald, b2, g, 1);
    // layer 3: g[100000,64] @ W3[64,32], H=1 -> d_out
    gemm_al<64, 32, 1><<<g256, 256, 0, stream>>>(g, W3, as3, ad3, h, als, ald);
    agg_h1<<<gAgg, 256, 0, stream>>>(cnt, srcs, h, als, ald, b3, out);
}

// Round 12
// 353.612 us; speedup vs baseline: 1.0172x; 1.0172x over previous
//
#include <hip/hip_runtime.h>
#include <hip/hip_fp16.h>

#define N_NODES 100000
#define N_EDGES 1600000
#define NPART   8
#define PART_SZ (N_NODES / NPART)   // 12500 (agg node mapping)
#define CAP 48                      // bucket capacity; degree ~ Poisson(16), P(>=48) ~ 1e-9
#define BSH  10                     // nodes per fill bin = 1024 (node-exclusive block ownership)
#define NBIN 98                     // ceil(100000 / 1024)
#define SCAP2 4096                  // per-(bin,stripe) staging cap: mean 2048, sigma 45 -> +45 sigma
#define SSH2 12                     // log2(SCAP2)
#define EPB  2048                   // edges per build block

static __device__ __forceinline__ float lrelu(float z) { return z > 0.f ? z : 0.2f * z; }
static __device__ __forceinline__ int imin(int a, int b) { return a < b ? a : b; }

// pack two floats into one u32 of fp16 pair (h payload is fp16 since round-9)
static __device__ __forceinline__ unsigned pack2h(float a, float b) {
    return __builtin_bit_cast(unsigned, __floats2half2_rn(a, b));
}

// ---------------- phase A: single-pass edge binning at 1024-node granularity ----------------
// (round-15: validated — bucket phase now ~25 us total, fill write-amp gone)
__global__ __launch_bounds__(256) void bucket_build(const int* __restrict__ ei, int* __restrict__ tails,
                                                    unsigned* __restrict__ stage) {
    __shared__ int lcnt[NBIN];
    __shared__ int lbase[NBIN];
    int tid = threadIdx.x;
    if (tid < NBIN) lcnt[tid] = 0;
    __syncthreads();

    int stripe = blockIdx.x & 7;
    int e0 = blockIdx.x * EPB;
    int binv[EPB / 256];
    int slotv[EPB / 256];
    unsigned vv[EPB / 256];
#pragma unroll
    for (int k = 0; k < EPB / 256; ++k) {
        int t = e0 + k * 256 + tid;
        binv[k] = -1;
        if (t < N_EDGES) {
            int d = __builtin_nontemporal_load(ei + N_EDGES + t);
            int s = __builtin_nontemporal_load(ei + t);
            int b = d >> BSH;
            vv[k] = ((unsigned)(d & ((1 << BSH) - 1)) << 17) | (unsigned)s;  // dloc 10b | src 17b
            slotv[k] = atomicAdd(&lcnt[b], 1);
            binv[k] = b;
        }
    }
    __syncthreads();

    if (tid < NBIN) lbase[tid] = atomicAdd(&tails[stripe * 128 + tid], lcnt[tid]);
    __syncthreads();

#pragma unroll
    for (int k = 0; k < EPB / 256; ++k) {
        if (binv[k] >= 0) {
            int pos = lbase[binv[k]] + slotv[k];
            if (pos < SCAP2)
                stage[((((unsigned)binv[k] << 3) | (unsigned)stripe) << SSH2) + (unsigned)pos] = vv[k];
        }
    }
}

// ---------------- phase B: node-exclusive bucket assembly, LDS counters only ----------------
__global__ __launch_bounds__(1024) void bucket_fill(const int* __restrict__ tails, const unsigned* __restrict__ stage,
                                                    int* __restrict__ cnt, int* __restrict__ srcs) {
    __shared__ int lc[1 << BSH];
    int tid = threadIdx.x;
    int bin = blockIdx.x;
    int base = bin << BSH;
    int nn = N_NODES - base; if (nn > (1 << BSH)) nn = 1 << BSH;
    if (tid < nn) {
        lc[tid] = 1;                           // self-loop occupies slot 0
        srcs[(base + tid) * CAP] = base + tid;
    }
    __syncthreads();

    for (int st = 0; st < 8; ++st) {
        int len = tails[st * 128 + bin];
        if (len > SCAP2) len = SCAP2;
        const unsigned* sl = stage + ((((unsigned)bin << 3) | (unsigned)st) << SSH2);
        for (int i = tid; i < len; i += 1024) {
            unsigned v = __builtin_nontemporal_load(sl + i);
            int dloc = (int)(v >> 17);
            int s = (int)(v & 0x1FFFFu);
            int slot = atomicAdd(&lc[dloc], 1);
            if (slot < CAP) srcs[(base + dloc) * CAP + slot] = s;
        }
    }
    __syncthreads();
    if (tid < nn) cnt[base + tid] = lc[tid];   // agg clamps deg > CAP
}

// ---------------- fused GEMM + attention logits (occupancy-first, k-chunked LDS) ----------------
// Round-22: rounds 8/10/11 all ~51-55 us at 22% VALU across three different inner-loop
// structures. What varied was OCCUPANCY (31/24/17.6%) — and duration didn't move.
// Diagnosis: the binding constraint is RESIDENT WAVES, not pipes. R11's NPB=128 cut
// the grid to 782 blocks = 3/CU available; per-SIMD ~1.4 waves ran the ds_read->FMA
// chain at latency. VALU demand is only ~10.4 us of 53 -> 22%, exactly measured.
// Fix: NPB=64 (grid 1563 = 6.1 blocks/CU), KCH=32 chunks -> LDS 16.9 KB (9 blocks/CU
// capacity), launch_bounds(256,8) pins VGPR<=64. Resident waves/CU ~12 -> ~24.
template <int IN, int OUT, int HEADS>
__global__ __launch_bounds__(256, 8) void gemm_al(const float* __restrict__ x, const float* __restrict__ W,
                                                  const float* __restrict__ asrc, const float* __restrict__ adst,
                                                  unsigned short* __restrict__ h, float* __restrict__ als,
                                                  float* __restrict__ ald) {
    constexpr int SPLIT = OUT / 16;            // col-slices (4 or 2)
    constexpr int NPB = 256 / SPLIT;           // rows per block: 64 (L1/L2) or 128 (L3)
    constexpr int KCH = 32;                    // k-chunk
    constexpr int KST = KCH + 1;               // padded stride: 33 -> conflict-free
    __shared__ alignas(16) float sx[NPB * KST];
    __shared__ alignas(16) float sw[KCH * OUT];
    int t = threadIdx.x;
    long base = (long)blockIdx.x * NPB;

    int w = t >> 6, lane = t & 63;
    int s = __builtin_amdgcn_readfirstlane(w % SPLIT);
    int rg = __builtin_amdgcn_readfirstlane(w / SPLIT);
    int r = rg * 64 + lane;                    // SPLIT=4: rg=0, r=lane; SPLIT=2: r in 0..127
    long n = base + r;

    float acc[16];
#pragma unroll
    for (int j = 0; j < 16; ++j) acc[j] = 0.f;

    for (int k0 = 0; k0 < IN; k0 += KCH) {
        __syncthreads();                       // prior chunk fully consumed
        // stage x chunk: NPB rows x KCH floats (float4 granularity, 8 f4/row)
#pragma unroll
        for (int e = t; e < NPB * (KCH / 4); e += 256) {
            int row = e >> 3, c4 = e & 7;
            long gr = base + row;
            if (gr >= N_NODES) gr = N_NODES - 1;
            float4 v = *reinterpret_cast<const float4*>(&x[gr * IN + k0 + c4 * 4]);
            float* d = &sx[row * KST + c4 * 4];
            d[0] = v.x; d[1] = v.y; d[2] = v.z; d[3] = v.w;
        }
        // stage W chunk: KCH x OUT floats, fully coalesced
#pragma unroll
        for (int e = t; e < KCH * OUT / 4; e += 256)
            reinterpret_cast<float4*>(sw)[e] =
                reinterpret_cast<const float4*>(W + (long)k0 * OUT)[e];
        __syncthreads();                       // chunk ready

        const float* swb = sw + s * 16;
#pragma unroll 8
        for (int k = 0; k < KCH; ++k) {
            float xv = sx[r * KST + k];
            const float* Wr = swb + k * OUT;
#pragma unroll
            for (int j = 0; j < 16; ++j) acc[j] = fmaf(xv, Wr[j], acc[j]);
        }
    }

    if (n < N_NODES) {
        unsigned u[8];
#pragma unroll
        for (int k = 0; k < 8; ++k) u[k] = pack2h(acc[2 * k], acc[2 * k + 1]);
        uint4* dst = reinterpret_cast<uint4*>(&h[n * OUT + s * 16]);
        dst[0] = make_uint4(u[0], u[1], u[2], u[3]);
        dst[1] = make_uint4(u[4], u[5], u[6], u[7]);
    }

    float ps = 0.f, pd = 0.f;
#pragma unroll
    for (int j = 0; j < 16; ++j) {
        ps = fmaf(acc[j], asrc[s * 16 + j], ps);
        pd = fmaf(acc[j], adst[s * 16 + j], pd);
    }
    if (HEADS == SPLIT) {                      // layers 1-2: slice s IS head s
        if (n < N_NODES) {
            als[n * HEADS + s] = ps;
            ald[n * HEADS + s] = pd;
        }
    } else {                                   // layer 3: sum the SPLIT col-slices
        __syncthreads();
        sx[r * 2 + s] = ps;
        sx[NPB * 2 + r * 2 + s] = pd;
        __syncthreads();
        if (t < NPB) {
            long nn = base + t;
            if (nn < N_NODES) {
                als[nn] = sx[t * 2] + sx[t * 2 + 1];
                ald[nn] = sx[NPB * 2 + t * 2] + sx[NPB * 2 + t * 2 + 1];
            }
        }
    }
}

// XCD-aligned node mapping for agg: XCD k (blockIdx&7) processes dst range k.
static __device__ __forceinline__ int agg_node(int blk, int wid) {
    return (blk & 7) * PART_SZ + (blk >> 3) * 4 + wid;
}

// ---------------- aggregation, H=4 C=16, fp16 payload, uint4 lanes ----------------
// Round-18's branchless depth-4 prefetch validated (VGPR=24-28 = loads live across the
// fence; VALU 67-69%). fp16 payload since round-9. Untouched this round (isolate gemm).
__global__ __launch_bounds__(256, 8) void agg_h4(const int* __restrict__ cnt, const int* __restrict__ srcs,
                                                 const unsigned short* __restrict__ h, const float* __restrict__ als,
                                                 const float* __restrict__ ald, const float* __restrict__ bias,
                                                 float* __restrict__ g, int do_relu) {
    const uint4* hrow = reinterpret_cast<const uint4*>(h);   // 8 uint4 per 64-ch row
    int wid = threadIdx.x >> 6, lane = threadIdx.x & 63;
    int n = agg_node(blockIdx.x, wid);
    if (n >= N_NODES) return;
    int q = lane >> 3, cc = lane & 7;
    int hd = cc >> 1;
    float ad = ald[n * 4 + hd];
    int deg = cnt[n]; if (deg > CAP) deg = CAP;   // deg >= 1 (self-loop), wave-uniform
    int dm1 = deg - 1;
    int sl = srcs[n * CAP + imin(lane, dm1)];     // whole bucket, one coalesced load

    // addresses (shfl chain), then 8 independent loads, all before the fence
    int s0 = __shfl(sl, imin(0 * 8 + q, dm1));
    int s1 = __shfl(sl, imin(1 * 8 + q, dm1));
    int s2 = __shfl(sl, imin(2 * 8 + q, dm1));
    int s3 = __shfl(sl, imin(3 * 8 + q, dm1));
    float al0 = als[s0 * 4 + hd];
    float al1 = als[s1 * 4 + hd];
    float al2 = als[s2 * 4 + hd];
    float al3 = als[s3 * 4 + hd];
    uint4 hv0 = hrow[(long)s0 * 8 + cc];
    uint4 hv1 = hrow[(long)s1 * 8 + cc];
    uint4 hv2 = hrow[(long)s2 * 8 + cc];
    uint4 hv3 = hrow[(long)s3 * 8 + cc];
    __builtin_amdgcn_sched_barrier(0);

    float a0 = 0.f, a1 = 0.f, a2 = 0.f, a3 = 0.f, a4 = 0.f, a5 = 0.f, a6 = 0.f, a7 = 0.f;
    float den = 0.f;
#define ACCUM(AL, HV, T)                                                \
    {                                                                   \
        float w = ((T) * 8 + q) < deg ? __expf(lrelu((AL) + ad)) : 0.f; \
        den += w;                                                       \
        __half2 p0 = __builtin_bit_cast(__half2, (HV).x);               \
        __half2 p1 = __builtin_bit_cast(__half2, (HV).y);               \
        __half2 p2 = __builtin_bit_cast(__half2, (HV).z);               \
        __half2 p3 = __builtin_bit_cast(__half2, (HV).w);               \
        a0 = fmaf(w, (float)p0.x, a0); a1 = fmaf(w, (float)p0.y, a1);   \
        a2 = fmaf(w, (float)p1.x, a2); a3 = fmaf(w, (float)p1.y, a3);   \
        a4 = fmaf(w, (float)p2.x, a4); a5 = fmaf(w, (float)p2.y, a5);   \
        a6 = fmaf(w, (float)p3.x, a6); a7 = fmaf(w, (float)p3.y, a7);   \
    }
    ACCUM(al0, hv0, 0)
    ACCUM(al1, hv1, 1)
    ACCUM(al2, hv2, 2)
    ACCUM(al3, hv3, 3)

    if (__builtin_expect(deg > 32, 0)) {          // wave-uniform rare tail
        for (int e = 32; e < deg; e += 8) {
            int ee = e + q;
            int s = __shfl(sl, imin(ee, dm1));
            float al = als[s * 4 + hd];
            uint4 hv = hrow[(long)s * 8 + cc];
            float w = ee < deg ? __expf(lrelu(al + ad)) : 0.f;
            den += w;
            __half2 p0 = __builtin_bit_cast(__half2, hv.x);
            __half2 p1 = __builtin_bit_cast(__half2, hv.y);
            __half2 p2 = __builtin_bit_cast(__half2, hv.z);
            __half2 p3 = __builtin_bit_cast(__half2, hv.w);
            a0 = fmaf(w, (float)p0.x, a0); a1 = fmaf(w, (float)p0.y, a1);
            a2 = fmaf(w, (float)p1.x, a2); a3 = fmaf(w, (float)p1.y, a3);
            a4 = fmaf(w, (float)p2.x, a4); a5 = fmaf(w, (float)p2.y, a5);
            a6 = fmaf(w, (float)p3.x, a6); a7 = fmaf(w, (float)p3.y, a7);
        }
    }
#undef ACCUM

#pragma unroll
    for (int d = 8; d <= 32; d <<= 1) {
        a0 += __shfl_xor(a0, d); a1 += __shfl_xor(a1, d);
        a2 += __shfl_xor(a2, d); a3 += __shfl_xor(a3, d);
        a4 += __shfl_xor(a4, d); a5 += __shfl_xor(a5, d);
        a6 += __shfl_xor(a6, d); a7 += __shfl_xor(a7, d);
        den += __shfl_xor(den, d);
    }
    if (q == 0) {
        float4 b0 = *reinterpret_cast<const float4*>(&bias[cc * 8]);
        float4 b1 = *reinterpret_cast<const float4*>(&bias[cc * 8 + 4]);
        float inv = 1.f / den;
        float4 o0, o1;
        o0.x = fmaf(a0, inv, b0.x); o0.y = fmaf(a1, inv, b0.y);
        o0.z = fmaf(a2, inv, b0.z); o0.w = fmaf(a3, inv, b0.w);
        o1.x = fmaf(a4, inv, b1.x); o1.y = fmaf(a5, inv, b1.y);
        o1.z = fmaf(a6, inv, b1.z); o1.w = fmaf(a7, inv, b1.w);
        if (do_relu) {
            o0.x = fmaxf(o0.x, 0.f); o0.y = fmaxf(o0.y, 0.f);
            o0.z = fmaxf(o0.z, 0.f); o0.w = fmaxf(o0.w, 0.f);
            o1.x = fmaxf(o1.x, 0.f); o1.y = fmaxf(o1.y, 0.f);
            o1.z = fmaxf(o1.z, 0.f); o1.w = fmaxf(o1.w, 0.f);
        }
        *reinterpret_cast<float4*>(&g[(long)n * 64 + cc * 8]) = o0;
        *reinterpret_cast<float4*>(&g[(long)n * 64 + cc * 8 + 4]) = o1;
    }
}

// ---------------- aggregation, H=1 C=32, fp16 payload, uint4 lanes ----------------
// Branchless fixed-depth-2 prefetch (16-edge groups, covers deg<=32) + rare tail.
__global__ __launch_bounds__(256, 8) void agg_h1(const int* __restrict__ cnt, const int* __restrict__ srcs,
                                                 const unsigned short* __restrict__ h3, const float* __restrict__ als,
                                                 const float* __restrict__ ald, const float* __restrict__ bias,
                                                 float* __restrict__ out) {
    const uint4* hrow = reinterpret_cast<const uint4*>(h3);  // 4 uint4 per 32-ch row
    int wid = threadIdx.x >> 6, lane = threadIdx.x & 63;
    int n = agg_node(blockIdx.x, wid);
    if (n >= N_NODES) return;
    int q = lane >> 2, cc = lane & 3;
    float ad = ald[n];
    int deg = cnt[n]; if (deg > CAP) deg = CAP;
    int dm1 = deg - 1;
    int sl = srcs[n * CAP + imin(lane, dm1)];

    int s0 = __shfl(sl, imin(0 * 16 + q, dm1));
    int s1 = __shfl(sl, imin(1 * 16 + q, dm1));
    float al0 = als[s0];
    float al1 = als[s1];
    uint4 hv0 = hrow[(long)s0 * 4 + cc];
    uint4 hv1 = hrow[(long)s1 * 4 + cc];
    __builtin_amdgcn_sched_barrier(0);

    float a0 = 0.f, a1 = 0.f, a2 = 0.f, a3 = 0.f, a4 = 0.f, a5 = 0.f, a6 = 0.f, a7 = 0.f;
    float den = 0.f;
#define ACCUM1(AL, HV, T)                                                \
    {                                                                    \
        float w = ((T) * 16 + q) < deg ? __expf(lrelu((AL) + ad)) : 0.f; \
        den += w;                                                        \
        __half2 p0 = __builtin_bit_cast(__half2, (HV).x);                \
        __half2 p1 = __builtin_bit_cast(__half2, (HV).y);                \
        __half2 p2 = __builtin_bit_cast(__half2, (HV).z);                \
        __half2 p3 = __builtin_bit_cast(__half2, (HV).w);                \
        a0 = fmaf(w, (float)p0.x, a0); a1 = fmaf(w, (float)p0.y, a1);    \
        a2 = fmaf(w, (float)p1.x, a2); a3 = fmaf(w, (float)p1.y, a3);    \
        a4 = fmaf(w, (float)p2.x, a4); a5 = fmaf(w, (float)p2.y, a5);    \
        a6 = fmaf(w, (float)p3.x, a6); a7 = fmaf(w, (float)p3.y, a7);    \
    }
    ACCUM1(al0, hv0, 0)
    ACCUM1(al1, hv1, 1)

    if (__builtin_expect(deg > 32, 0)) {          // wave-uniform rare tail
        for (int e = 32; e < deg; e += 16) {
            int ee = e + q;
            int s = __shfl(sl, imin(ee, dm1));
            float al = als[s];
            uint4 hv = hrow[(long)s * 4 + cc];
            float w = ee < deg ? __expf(lrelu(al + ad)) : 0.f;
            den += w;
            __half2 p0 = __builtin_bit_cast(__half2, hv.x);
            __half2 p1 = __builtin_bit_cast(__half2, hv.y);
            __half2 p2 = __builtin_bit_cast(__half2, hv.z);
            __half2 p3 = __builtin_bit_cast(__half2, hv.w);
            a0 = fmaf(w, (float)p0.x, a0); a1 = fmaf(w, (float)p0.y, a1);
            a2 = fmaf(w, (float)p1.x, a2); a3 = fmaf(w, (float)p1.y, a3);
            a4 = fmaf(w, (float)p2.x, a4); a5 = fmaf(w, (float)p2.y, a5);
            a6 = fmaf(w, (float)p3.x, a6); a7 = fmaf(w, (float)p3.y, a7);
        }
    }
#undef ACCUM1

#pragma unroll
    for (int d = 4; d <= 32; d <<= 1) {
        a0 += __shfl_xor(a0, d); a1 += __shfl_xor(a1, d);
        a2 += __shfl_xor(a2, d); a3 += __shfl_xor(a3, d);
        a4 += __shfl_xor(a4, d); a5 += __shfl_xor(a5, d);
        a6 += __shfl_xor(a6, d); a7 += __shfl_xor(a7, d);
        den += __shfl_xor(den, d);
    }
    if (q == 0) {
        float4 b0 = *reinterpret_cast<const float4*>(&bias[cc * 8]);
        float4 b1 = *reinterpret_cast<const float4*>(&bias[cc * 8 + 4]);
        float inv = 1.f / den;
        float4 o0, o1;
        o0.x = fmaf(a0, inv, b0.x); o0.y = fmaf(a1, inv, b0.y);
        o0.z = fmaf(a2, inv, b0.z); o0.w = fmaf(a3, inv, b0.w);
        o1.x = fmaf(a4, inv, b1.x); o1.y = fmaf(a5, inv, b1.y);
        o1.z = fmaf(a6, inv, b1.z); o1.w = fmaf(a7, inv, b1.w);
        *reinterpret_cast<float4*>(&out[(long)n * 32 + cc * 8]) = o0;
        *reinterpret_cast<float4*>(&out[(long)n * 32 + cc * 8 + 4]) = o1;
    }
}

extern "C" void kernel_launch(void* const* d_in, const int* in_sizes, int n_in,
                              void* d_out, int out_size, void* d_ws, size_t ws_size,
                              hipStream_t stream) {
    (void)in_sizes; (void)n_in; (void)out_size; (void)ws_size;
    const float* x   = (const float*)d_in[0];
    const int*   ei  = (const int*)d_in[1];
    const float* W1  = (const float*)d_in[2];
    const float* as1 = (const float*)d_in[3];
    const float* ad1 = (const float*)d_in[4];
    const float* b1  = (const float*)d_in[5];
    const float* W2  = (const float*)d_in[6];
    const float* as2 = (const float*)d_in[7];
    const float* ad2 = (const float*)d_in[8];
    const float* b2  = (const float*)d_in[9];
    const float* W3  = (const float*)d_in[10];
    const float* as3 = (const float*)d_in[11];
    const float* ad3 = (const float*)d_in[12];
    const float* b3  = (const float*)d_in[13];
    float* out = (float*)d_out;

    char* w = (char*)d_ws;
    auto alloc = [&](size_t bytes) {
        void* p = (void*)w;
        w += (bytes + 255) & ~(size_t)255;
        return p;
    };
    int*            cnt   = (int*)alloc((size_t)N_NODES * 4);
    int*            tails = (int*)alloc((size_t)1024 * 4);            // 8 stripes x 128-int pad
    int*            srcs  = (int*)alloc((size_t)N_NODES * CAP * 4);   // 19.2 MB
    unsigned short* h     = (unsigned short*)alloc((size_t)N_NODES * 64 * 2);  // fp16, 12.8 MB
    float*          g     = (float*)alloc((size_t)N_NODES * 64 * 4);  // 25.6 MB
    float*          als   = (float*)alloc((size_t)N_NODES * 4 * 4);
    float*          ald   = (float*)alloc((size_t)N_NODES * 4 * 4);
    // staging (12.85 MB) aliases g: consumed by bucket_fill before agg_h4 first writes g.
    unsigned*       stage = (unsigned*)g;

    hipMemsetAsync(tails, 0, (size_t)1024 * 4, stream);   // cnt memset no longer needed

    int g64  = (N_NODES + 63) / 64;    // 1563 (layers 1-2: NPB=64)
    int g128 = (N_NODES + 127) / 128;  // 782  (layer 3:   NPB=128)
    int gAgg = ((N_NODES + 3) / 4 + 7) & ~7;   // 25000 -> mult of 8
    int gBuild = (N_EDGES + EPB - 1) / EPB;    // 782 (self-loops not staged)

    bucket_build<<<gBuild, 256, 0, stream>>>(ei, tails, stage);
    bucket_fill<<<NBIN, 1024, 0, stream>>>(tails, stage, cnt, srcs);

    // layer 1: x[100000,128] @ W1[128,64], H=4
    gemm_al<128, 64, 4><<<g64, 256, 0, stream>>>(x, W1, as1, ad1, h, als, ald);
    agg_h4<<<gAgg, 256, 0, stream>>>(cnt, srcs, h, als, ald, b1, g, 1);
    // layer 2: g[100000,64] @ W2[64,64], H=4
    gemm_al<64, 64, 4><<<g64, 256, 0, stream>>>(g, W2, as2, ad2, h, als, ald);
    agg_h4<<<gAgg, 256, 0, stream>>>(cnt, srcs, h, als, ald, b2, g, 1);
    // layer 3: g[100000,64] @ W3[64,32], H=1 -> d_out
    gemm_al<64, 32, 1><<<g128, 256, 0, stream>>>(g, W3, as3, ad3, h, als, ald);
    agg_h1<<<gAgg, 256, 0, stream>>>(cnt, srcs, h, als, ald, b3, out);
}

// Round 13
// 347.785 us; speedup vs baseline: 1.0342x; 1.0168x over previous
//
#include <hip/hip_runtime.h>
#include <hip/hip_fp16.h>

#define N_NODES 100000
#define N_EDGES 1600000
#define NPART   8
#define PART_SZ (N_NODES / NPART)   // 12500 (agg node mapping)
#define CAP 48                      // bucket capacity; degree ~ Poisson(16), P(>=48) ~ 1e-9
#define BSH  10                     // nodes per fill bin = 1024 (node-exclusive block ownership)
#define NBIN 98                     // ceil(100000 / 1024)
#define SCAP2 4096                  // per-(bin,stripe) staging cap: mean 2048, sigma 45 -> +45 sigma
#define SSH2 12                     // log2(SCAP2)
#define EPB  2048                   // edges per build block

static __device__ __forceinline__ float lrelu(float z) { return z > 0.f ? z : 0.2f * z; }
static __device__ __forceinline__ int imin(int a, int b) { return a < b ? a : b; }

// pack two floats into one u32 of fp16 pair (h payload is fp16 since round-9)
static __device__ __forceinline__ unsigned pack2h(float a, float b) {
    return __builtin_bit_cast(unsigned, __floats2half2_rn(a, b));
}

// ---------------- phase A: single-pass edge binning at 1024-node granularity ----------------
// (round-15: validated — bucket phase now ~25 us total, fill write-amp gone)
__global__ __launch_bounds__(256) void bucket_build(const int* __restrict__ ei, int* __restrict__ tails,
                                                    unsigned* __restrict__ stage) {
    __shared__ int lcnt[NBIN];
    __shared__ int lbase[NBIN];
    int tid = threadIdx.x;
    if (tid < NBIN) lcnt[tid] = 0;
    __syncthreads();

    int stripe = blockIdx.x & 7;
    int e0 = blockIdx.x * EPB;
    int binv[EPB / 256];
    int slotv[EPB / 256];
    unsigned vv[EPB / 256];
#pragma unroll
    for (int k = 0; k < EPB / 256; ++k) {
        int t = e0 + k * 256 + tid;
        binv[k] = -1;
        if (t < N_EDGES) {
            int d = __builtin_nontemporal_load(ei + N_EDGES + t);
            int s = __builtin_nontemporal_load(ei + t);
            int b = d >> BSH;
            vv[k] = ((unsigned)(d & ((1 << BSH) - 1)) << 17) | (unsigned)s;  // dloc 10b | src 17b
            slotv[k] = atomicAdd(&lcnt[b], 1);
            binv[k] = b;
        }
    }
    __syncthreads();

    if (tid < NBIN) lbase[tid] = atomicAdd(&tails[stripe * 128 + tid], lcnt[tid]);
    __syncthreads();

#pragma unroll
    for (int k = 0; k < EPB / 256; ++k) {
        if (binv[k] >= 0) {
            int pos = lbase[binv[k]] + slotv[k];
            if (pos < SCAP2)
                stage[((((unsigned)binv[k] << 3) | (unsigned)stripe) << SSH2) + (unsigned)pos] = vv[k];
        }
    }
}

// ---------------- phase B: node-exclusive bucket assembly, LDS counters only ----------------
__global__ __launch_bounds__(1024) void bucket_fill(const int* __restrict__ tails, const unsigned* __restrict__ stage,
                                                    int* __restrict__ cnt, int* __restrict__ srcs) {
    __shared__ int lc[1 << BSH];
    int tid = threadIdx.x;
    int bin = blockIdx.x;
    int base = bin << BSH;
    int nn = N_NODES - base; if (nn > (1 << BSH)) nn = 1 << BSH;
    if (tid < nn) {
        lc[tid] = 1;                           // self-loop occupies slot 0
        srcs[(base + tid) * CAP] = base + tid;
    }
    __syncthreads();

    for (int st = 0; st < 8; ++st) {
        int len = tails[st * 128 + bin];
        if (len > SCAP2) len = SCAP2;
        const unsigned* sl = stage + ((((unsigned)bin << 3) | (unsigned)st) << SSH2);
        for (int i = tid; i < len; i += 1024) {
            unsigned v = __builtin_nontemporal_load(sl + i);
            int dloc = (int)(v >> 17);
            int s = (int)(v & 0x1FFFFu);
            int slot = atomicAdd(&lc[dloc], 1);
            if (slot < CAP) srcs[(base + dloc) * CAP + slot] = s;
        }
    }
    __syncthreads();
    if (tid < nn) cnt[base + tid] = lc[tid];   // agg clamps deg > CAP
}

// ---------------- fused GEMM + attention logits (occupancy-first, k-chunked LDS) ----------------
// Round-22 (validated): gemm was resident-wave-starved (grid 782 = 3 blocks/CU); NPB=64
// grid 1563 + 16.9 KB LDS + launch_bounds(256,8) restored ~24 waves/CU — gemm dropped
// out of the top-5 dispatches.
template <int IN, int OUT, int HEADS>
__global__ __launch_bounds__(256, 8) void gemm_al(const float* __restrict__ x, const float* __restrict__ W,
                                                  const float* __restrict__ asrc, const float* __restrict__ adst,
                                                  unsigned short* __restrict__ h, float* __restrict__ als,
                                                  float* __restrict__ ald) {
    constexpr int SPLIT = OUT / 16;            // col-slices (4 or 2)
    constexpr int NPB = 256 / SPLIT;           // rows per block: 64 (L1/L2) or 128 (L3)
    constexpr int KCH = 32;                    // k-chunk
    constexpr int KST = KCH + 1;               // padded stride: 33 -> conflict-free
    __shared__ alignas(16) float sx[NPB * KST];
    __shared__ alignas(16) float sw[KCH * OUT];
    int t = threadIdx.x;
    long base = (long)blockIdx.x * NPB;

    int w = t >> 6, lane = t & 63;
    int s = __builtin_amdgcn_readfirstlane(w % SPLIT);
    int rg = __builtin_amdgcn_readfirstlane(w / SPLIT);
    int r = rg * 64 + lane;                    // SPLIT=4: rg=0, r=lane; SPLIT=2: r in 0..127
    long n = base + r;

    float acc[16];
#pragma unroll
    for (int j = 0; j < 16; ++j) acc[j] = 0.f;

    for (int k0 = 0; k0 < IN; k0 += KCH) {
        __syncthreads();                       // prior chunk fully consumed
        // stage x chunk: NPB rows x KCH floats (float4 granularity, 8 f4/row)
#pragma unroll
        for (int e = t; e < NPB * (KCH / 4); e += 256) {
            int row = e >> 3, c4 = e & 7;
            long gr = base + row;
            if (gr >= N_NODES) gr = N_NODES - 1;
            float4 v = *reinterpret_cast<const float4*>(&x[gr * IN + k0 + c4 * 4]);
            float* d = &sx[row * KST + c4 * 4];
            d[0] = v.x; d[1] = v.y; d[2] = v.z; d[3] = v.w;
        }
        // stage W chunk: KCH x OUT floats, fully coalesced
#pragma unroll
        for (int e = t; e < KCH * OUT / 4; e += 256)
            reinterpret_cast<float4*>(sw)[e] =
                reinterpret_cast<const float4*>(W + (long)k0 * OUT)[e];
        __syncthreads();                       // chunk ready

        const float* swb = sw + s * 16;
#pragma unroll 8
        for (int k = 0; k < KCH; ++k) {
            float xv = sx[r * KST + k];
            const float* Wr = swb + k * OUT;
#pragma unroll
            for (int j = 0; j < 16; ++j) acc[j] = fmaf(xv, Wr[j], acc[j]);
        }
    }

    if (n < N_NODES) {
        unsigned u[8];
#pragma unroll
        for (int k = 0; k < 8; ++k) u[k] = pack2h(acc[2 * k], acc[2 * k + 1]);
        uint4* dst = reinterpret_cast<uint4*>(&h[n * OUT + s * 16]);
        dst[0] = make_uint4(u[0], u[1], u[2], u[3]);
        dst[1] = make_uint4(u[4], u[5], u[6], u[7]);
    }

    float ps = 0.f, pd = 0.f;
#pragma unroll
    for (int j = 0; j < 16; ++j) {
        ps = fmaf(acc[j], asrc[s * 16 + j], ps);
        pd = fmaf(acc[j], adst[s * 16 + j], pd);
    }
    if (HEADS == SPLIT) {                      // layers 1-2: slice s IS head s
        if (n < N_NODES) {
            als[n * HEADS + s] = ps;
            ald[n * HEADS + s] = pd;
        }
    } else {                                   // layer 3: sum the SPLIT col-slices
        __syncthreads();
        sx[r * 2 + s] = ps;
        sx[NPB * 2 + r * 2 + s] = pd;
        __syncthreads();
        if (t < NPB) {
            long nn = base + t;
            if (nn < N_NODES) {
                als[nn] = sx[t * 2] + sx[t * 2 + 1];
                ald[nn] = sx[NPB * 2 + t * 2] + sx[NPB * 2 + t * 2 + 1];
            }
        }
    }
}

// XCD-aligned node mapping for agg: XCD k (blockIdx&7) processes dst range k.
static __device__ __forceinline__ int agg_node(int blk, int wid) {
    return (blk & 7) * PART_SZ + (blk >> 3) * 4 + wid;
}

// ---------------- degree-adaptive straight-line bodies ----------------
// Round-23: the fixed depth-4 pipeline always issued 4 edge-groups but Poisson(16)+1
// degrees need only E[ceil(deg/8)] ~ 2.56 — ~36% of loads/exp/FMA were clamped
// duplicates masked to zero. nit is WAVE-UNIFORM -> scalar switch to templated
// single-basic-block bodies (all loads unguarded up-front per case: the round-8
// no-sink property holds per-case; round-6's guarded-load re-serialization avoided).
template <int NG>
static __device__ __forceinline__ void agg4_run(
    int sl, int deg, int dm1, int q, int cc, int hd, float ad,
    const uint4* __restrict__ hrow, const float* __restrict__ als,
    float& a0, float& a1, float& a2, float& a3,
    float& a4, float& a5, float& a6, float& a7, float& den)
{
    int sv[NG]; float alv[NG]; uint4 hv[NG];
#pragma unroll
    for (int t = 0; t < NG; ++t) sv[t] = __shfl(sl, imin(t * 8 + q, dm1));
#pragma unroll
    for (int t = 0; t < NG; ++t) alv[t] = als[sv[t] * 4 + hd];
#pragma unroll
    for (int t = 0; t < NG; ++t) hv[t] = hrow[(long)sv[t] * 8 + cc];
    __builtin_amdgcn_sched_barrier(0);
#pragma unroll
    for (int t = 0; t < NG; ++t) {
        float w = (t * 8 + q) < deg ? __expf(lrelu(alv[t] + ad)) : 0.f;
        den += w;
        __half2 p0 = __builtin_bit_cast(__half2, hv[t].x);
        __half2 p1 = __builtin_bit_cast(__half2, hv[t].y);
        __half2 p2 = __builtin_bit_cast(__half2, hv[t].z);
        __half2 p3 = __builtin_bit_cast(__half2, hv[t].w);
        a0 = fmaf(w, (float)p0.x, a0); a1 = fmaf(w, (float)p0.y, a1);
        a2 = fmaf(w, (float)p1.x, a2); a3 = fmaf(w, (float)p1.y, a3);
        a4 = fmaf(w, (float)p2.x, a4); a5 = fmaf(w, (float)p2.y, a5);
        a6 = fmaf(w, (float)p3.x, a6); a7 = fmaf(w, (float)p3.y, a7);
    }
}

template <int NG>
static __device__ __forceinline__ void agg1_run(
    int sl, int deg, int dm1, int q, int cc, float ad,
    const uint4* __restrict__ hrow, const float* __restrict__ als,
    float& a0, float& a1, float& a2, float& a3,
    float& a4, float& a5, float& a6, float& a7, float& den)
{
    int sv[NG]; float alv[NG]; uint4 hv[NG];
#pragma unroll
    for (int t = 0; t < NG; ++t) sv[t] = __shfl(sl, imin(t * 16 + q, dm1));
#pragma unroll
    for (int t = 0; t < NG; ++t) alv[t] = als[sv[t]];
#pragma unroll
    for (int t = 0; t < NG; ++t) hv[t] = hrow[(long)sv[t] * 4 + cc];
    __builtin_amdgcn_sched_barrier(0);
#pragma unroll
    for (int t = 0; t < NG; ++t) {
        float w = (t * 16 + q) < deg ? __expf(lrelu(alv[t] + ad)) : 0.f;
        den += w;
        __half2 p0 = __builtin_bit_cast(__half2, hv[t].x);
        __half2 p1 = __builtin_bit_cast(__half2, hv[t].y);
        __half2 p2 = __builtin_bit_cast(__half2, hv[t].z);
        __half2 p3 = __builtin_bit_cast(__half2, hv[t].w);
        a0 = fmaf(w, (float)p0.x, a0); a1 = fmaf(w, (float)p0.y, a1);
        a2 = fmaf(w, (float)p1.x, a2); a3 = fmaf(w, (float)p1.y, a3);
        a4 = fmaf(w, (float)p2.x, a4); a5 = fmaf(w, (float)p2.y, a5);
        a6 = fmaf(w, (float)p3.x, a6); a7 = fmaf(w, (float)p3.y, a7);
    }
}

// ---------------- aggregation, H=4 C=16, fp16 payload, uint4 lanes ----------------
__global__ __launch_bounds__(256, 8) void agg_h4(const int* __restrict__ cnt, const int* __restrict__ srcs,
                                                 const unsigned short* __restrict__ h, const float* __restrict__ als,
                                                 const float* __restrict__ ald, const float* __restrict__ bias,
                                                 float* __restrict__ g, int do_relu) {
    const uint4* hrow = reinterpret_cast<const uint4*>(h);   // 8 uint4 per 64-ch row
    int wid = threadIdx.x >> 6, lane = threadIdx.x & 63;
    int n = agg_node(blockIdx.x, wid);
    if (n >= N_NODES) return;
    int q = lane >> 3, cc = lane & 7;
    int hd = cc >> 1;
    float ad = ald[n * 4 + hd];
    int deg = cnt[n]; if (deg > CAP) deg = CAP;   // deg >= 1 (self-loop), wave-uniform
    int dm1 = deg - 1;
    int sl = srcs[n * CAP + imin(lane, dm1)];     // whole bucket, one coalesced load

    float a0 = 0.f, a1 = 0.f, a2 = 0.f, a3 = 0.f, a4 = 0.f, a5 = 0.f, a6 = 0.f, a7 = 0.f;
    float den = 0.f;

    switch ((deg + 7) >> 3) {                     // wave-uniform scalar dispatch
    case 1: agg4_run<1>(sl, deg, dm1, q, cc, hd, ad, hrow, als, a0, a1, a2, a3, a4, a5, a6, a7, den); break;
    case 2: agg4_run<2>(sl, deg, dm1, q, cc, hd, ad, hrow, als, a0, a1, a2, a3, a4, a5, a6, a7, den); break;
    case 3: agg4_run<3>(sl, deg, dm1, q, cc, hd, ad, hrow, als, a0, a1, a2, a3, a4, a5, a6, a7, den); break;
    default:
        agg4_run<4>(sl, deg, dm1, q, cc, hd, ad, hrow, als, a0, a1, a2, a3, a4, a5, a6, a7, den);
        if (__builtin_expect(deg > 32, 0)) {      // wave-uniform rare tail
            for (int e = 32; e < deg; e += 8) {
                int ee = e + q;
                int s = __shfl(sl, imin(ee, dm1));
                float al = als[s * 4 + hd];
                uint4 hv = hrow[(long)s * 8 + cc];
                float w = ee < deg ? __expf(lrelu(al + ad)) : 0.f;
                den += w;
                __half2 p0 = __builtin_bit_cast(__half2, hv.x);
                __half2 p1 = __builtin_bit_cast(__half2, hv.y);
                __half2 p2 = __builtin_bit_cast(__half2, hv.z);
                __half2 p3 = __builtin_bit_cast(__half2, hv.w);
                a0 = fmaf(w, (float)p0.x, a0); a1 = fmaf(w, (float)p0.y, a1);
                a2 = fmaf(w, (float)p1.x, a2); a3 = fmaf(w, (float)p1.y, a3);
                a4 = fmaf(w, (float)p2.x, a4); a5 = fmaf(w, (float)p2.y, a5);
                a6 = fmaf(w, (float)p3.x, a6); a7 = fmaf(w, (float)p3.y, a7);
            }
        }
        break;
    }

#pragma unroll
    for (int d = 8; d <= 32; d <<= 1) {
        a0 += __shfl_xor(a0, d); a1 += __shfl_xor(a1, d);
        a2 += __shfl_xor(a2, d); a3 += __shfl_xor(a3, d);
        a4 += __shfl_xor(a4, d); a5 += __shfl_xor(a5, d);
        a6 += __shfl_xor(a6, d); a7 += __shfl_xor(a7, d);
        den += __shfl_xor(den, d);
    }
    if (q == 0) {
        float4 b0 = *reinterpret_cast<const float4*>(&bias[cc * 8]);
        float4 b1 = *reinterpret_cast<const float4*>(&bias[cc * 8 + 4]);
        float inv = 1.f / den;
        float4 o0, o1;
        o0.x = fmaf(a0, inv, b0.x); o0.y = fmaf(a1, inv, b0.y);
        o0.z = fmaf(a2, inv, b0.z); o0.w = fmaf(a3, inv, b0.w);
        o1.x = fmaf(a4, inv, b1.x); o1.y = fmaf(a5, inv, b1.y);
        o1.z = fmaf(a6, inv, b1.z); o1.w = fmaf(a7, inv, b1.w);
        if (do_relu) {
            o0.x = fmaxf(o0.x, 0.f); o0.y = fmaxf(o0.y, 0.f);
            o0.z = fmaxf(o0.z, 0.f); o0.w = fmaxf(o0.w, 0.f);
            o1.x = fmaxf(o1.x, 0.f); o1.y = fmaxf(o1.y, 0.f);
            o1.z = fmaxf(o1.z, 0.f); o1.w = fmaxf(o1.w, 0.f);
        }
        *reinterpret_cast<float4*>(&g[(long)n * 64 + cc * 8]) = o0;
        *reinterpret_cast<float4*>(&g[(long)n * 64 + cc * 8 + 4]) = o1;
    }
}

// ---------------- aggregation, H=1 C=32, fp16 payload, uint4 lanes ----------------
// NG in {1,2,3} covers deg <= 48 entirely (old deg>32 tail absorbed by case 3).
__global__ __launch_bounds__(256, 8) void agg_h1(const int* __restrict__ cnt, const int* __restrict__ srcs,
                                                 const unsigned short* __restrict__ h3, const float* __restrict__ als,
                                                 const float* __restrict__ ald, const float* __restrict__ bias,
                                                 float* __restrict__ out) {
    const uint4* hrow = reinterpret_cast<const uint4*>(h3);  // 4 uint4 per 32-ch row
    int wid = threadIdx.x >> 6, lane = threadIdx.x & 63;
    int n = agg_node(blockIdx.x, wid);
    if (n >= N_NODES) return;
    int q = lane >> 2, cc = lane & 3;
    float ad = ald[n];
    int deg = cnt[n]; if (deg > CAP) deg = CAP;
    int dm1 = deg - 1;
    int sl = srcs[n * CAP + imin(lane, dm1)];

    float a0 = 0.f, a1 = 0.f, a2 = 0.f, a3 = 0.f, a4 = 0.f, a5 = 0.f, a6 = 0.f, a7 = 0.f;
    float den = 0.f;

    switch ((deg + 15) >> 4) {                    // wave-uniform scalar dispatch
    case 1: agg1_run<1>(sl, deg, dm1, q, cc, ad, hrow, als, a0, a1, a2, a3, a4, a5, a6, a7, den); break;
    case 2: agg1_run<2>(sl, deg, dm1, q, cc, ad, hrow, als, a0, a1, a2, a3, a4, a5, a6, a7, den); break;
    default: agg1_run<3>(sl, deg, dm1, q, cc, ad, hrow, als, a0, a1, a2, a3, a4, a5, a6, a7, den); break;
    }

#pragma unroll
    for (int d = 4; d <= 32; d <<= 1) {
        a0 += __shfl_xor(a0, d); a1 += __shfl_xor(a1, d);
        a2 += __shfl_xor(a2, d); a3 += __shfl_xor(a3, d);
        a4 += __shfl_xor(a4, d); a5 += __shfl_xor(a5, d);
        a6 += __shfl_xor(a6, d); a7 += __shfl_xor(a7, d);
        den += __shfl_xor(den, d);
    }
    if (q == 0) {
        float4 b0 = *reinterpret_cast<const float4*>(&bias[cc * 8]);
        float4 b1 = *reinterpret_cast<const float4*>(&bias[cc * 8 + 4]);
        float inv = 1.f / den;
        float4 o0, o1;
        o0.x = fmaf(a0, inv, b0.x); o0.y = fmaf(a1, inv, b0.y);
        o0.z = fmaf(a2, inv, b0.z); o0.w = fmaf(a3, inv, b0.w);
        o1.x = fmaf(a4, inv, b1.x); o1.y = fmaf(a5, inv, b1.y);
        o1.z = fmaf(a6, inv, b1.z); o1.w = fmaf(a7, inv, b1.w);
        *reinterpret_cast<float4*>(&out[(long)n * 32 + cc * 8]) = o0;
        *reinterpret_cast<float4*>(&out[(long)n * 32 + cc * 8 + 4]) = o1;
    }
}

extern "C" void kernel_launch(void* const* d_in, const int* in_sizes, int n_in,
                              void* d_out, int out_size, void* d_ws, size_t ws_size,
                              hipStream_t stream) {
    (void)in_sizes; (void)n_in; (void)out_size; (void)ws_size;
    const float* x   = (const float*)d_in[0];
    const int*   ei  = (const int*)d_in[1];
    const float* W1  = (const float*)d_in[2];
    const float* as1 = (const float*)d_in[3];
    const float* ad1 = (const float*)d_in[4];
    const float* b1  = (const float*)d_in[5];
    const float* W2  = (const float*)d_in[6];
    const float* as2 = (const float*)d_in[7];
    const float* ad2 = (const float*)d_in[8];
    const float* b2  = (const float*)d_in[9];
    const float* W3  = (const float*)d_in[10];
    const float* as3 = (const float*)d_in[11];
    const float* ad3 = (const float*)d_in[12];
    const float* b3  = (const float*)d_in[13];
    float* out = (float*)d_out;

    char* w = (char*)d_ws;
    auto alloc = [&](size_t bytes) {
        void* p = (void*)w;
        w += (bytes + 255) & ~(size_t)255;
        return p;
    };
    int*            cnt   = (int*)alloc((size_t)N_NODES * 4);
    int*            tails = (int*)alloc((size_t)1024 * 4);            // 8 stripes x 128-int pad
    int*            srcs  = (int*)alloc((size_t)N_NODES * CAP * 4);   // 19.2 MB
    unsigned short* h     = (unsigned short*)alloc((size_t)N_NODES * 64 * 2);  // fp16, 12.8 MB
    float*          g     = (float*)alloc((size_t)N_NODES * 64 * 4);  // 25.6 MB
    float*          als   = (float*)alloc((size_t)N_NODES * 4 * 4);
    float*          ald   = (float*)alloc((size_t)N_NODES * 4 * 4);
    // staging (12.85 MB) aliases g: consumed by bucket_fill before agg_h4 first writes g.
    unsigned*       stage = (unsigned*)g;

    hipMemsetAsync(tails, 0, (size_t)1024 * 4, stream);   // cnt memset no longer needed

    int g64  = (N_NODES + 63) / 64;    // 1563 (layers 1-2: NPB=64)
    int g128 = (N_NODES + 127) / 128;  // 782  (layer 3:   NPB=128)
    int gAgg = ((N_NODES + 3) / 4 + 7) & ~7;   // 25000 -> mult of 8
    int gBuild = (N_EDGES + EPB - 1) / EPB;    // 782 (self-loops not staged)

    bucket_build<<<gBuild, 256, 0, stream>>>(ei, tails, stage);
    bucket_fill<<<NBIN, 1024, 0, stream>>>(tails, stage, cnt, srcs);

    // layer 1: x[100000,128] @ W1[128,64], H=4
    gemm_al<128, 64, 4><<<g64, 256, 0, stream>>>(x, W1, as1, ad1, h, als, ald);
    agg_h4<<<gAgg, 256, 0, stream>>>(cnt, srcs, h, als, ald, b1, g, 1);
    // layer 2: g[100000,64] @ W2[64,64], H=4
    gemm_al<64, 64, 4><<<g64, 256, 0, stream>>>(g, W2, as2, ad2, h, als, ald);
    agg_h4<<<gAgg, 256, 0, stream>>>(cnt, srcs, h, als, ald, b2, g, 1);
    // layer 3: g[100000,64] @ W3[64,32], H=1 -> d_out
    gemm_al<64, 32, 1><<<g128, 256, 0, stream>>>(g, W3, as3, ad3, h, als, ald);
    agg_h1<<<gAgg, 256, 0, stream>>>(cnt, srcs, h, als, ald, b3, out);
}

// Round 14
// 337.500 us; speedup vs baseline: 1.0657x; 1.0305x over previous
//
#include <hip/hip_runtime.h>
#include <hip/hip_fp16.h>

#define N_NODES 100000
#define N_EDGES 1600000
#define NPART   8
#define PART_SZ (N_NODES / NPART)   // 12500 (agg node mapping)
#define CAP 48                      // bucket capacity; degree ~ Poisson(16), P(>=48) ~ 1e-9
#define BSH  10                     // nodes per fill bin = 1024 (node-exclusive block ownership)
#define NBIN 98                     // ceil(100000 / 1024)
#define SCAP2 4096                  // per-(bin,stripe) staging cap: mean 2048, sigma 45 -> +45 sigma
#define SSH2 12                     // log2(SCAP2)
#define EPB  2048                   // edges per build block
#define G64  ((N_NODES + 63) / 64)  // 1563: gemm-role blocks in the fused dispatch
#define GBUILD ((N_EDGES + EPB - 1) / EPB)  // 782: build-role blocks

static __device__ __forceinline__ float lrelu(float z) { return z > 0.f ? z : 0.2f * z; }
static __device__ __forceinline__ int imin(int a, int b) { return a < b ? a : b; }

// pack two floats into one u32 of fp16 pair (h payload is fp16 since round-9)
static __device__ __forceinline__ unsigned pack2h(float a, float b) {
    return __builtin_bit_cast(unsigned, __floats2half2_rn(a, b));
}

// ---------------- build body: single-pass edge binning at 1024-node granularity ----------------
// (round-15: validated; round-24: fused into the layer-1 gemm dispatch — build reads ei,
// gemm reads x/W1; fully independent -> grid-role split overlaps build's ~13 us under
// the gemm's stalls instead of serializing it.)
static __device__ void build_body(int bid, const int* __restrict__ ei, int* __restrict__ tails,
                                  unsigned* __restrict__ stage) {
    __shared__ int lcnt[NBIN];
    __shared__ int lbase[NBIN];
    int tid = threadIdx.x;
    if (tid < NBIN) lcnt[tid] = 0;
    __syncthreads();

    int stripe = bid & 7;
    int e0 = bid * EPB;
    int binv[EPB / 256];
    int slotv[EPB / 256];
    unsigned vv[EPB / 256];
#pragma unroll
    for (int k = 0; k < EPB / 256; ++k) {
        int t = e0 + k * 256 + tid;
        binv[k] = -1;
        if (t < N_EDGES) {
            int d = __builtin_nontemporal_load(ei + N_EDGES + t);
            int s = __builtin_nontemporal_load(ei + t);
            int b = d >> BSH;
            vv[k] = ((unsigned)(d & ((1 << BSH) - 1)) << 17) | (unsigned)s;  // dloc 10b | src 17b
            slotv[k] = atomicAdd(&lcnt[b], 1);
            binv[k] = b;
        }
    }
    __syncthreads();

    if (tid < NBIN) lbase[tid] = atomicAdd(&tails[stripe * 128 + tid], lcnt[tid]);
    __syncthreads();

#pragma unroll
    for (int k = 0; k < EPB / 256; ++k) {
        if (binv[k] >= 0) {
            int pos = lbase[binv[k]] + slotv[k];
            if (pos < SCAP2)
                stage[((((unsigned)binv[k] << 3) | (unsigned)stripe) << SSH2) + (unsigned)pos] = vv[k];
        }
    }
}

// ---------------- gemm body (occupancy-first, k-chunked LDS) ----------------
// Round-22: grid-residency fix (NPB=64, 16.9 KB LDS, launch_bounds(256,8)).
// NOTE (round-24): gemm inner-loop is ~50 us across 5 structural variants and
// occupancies 17.6-41% with no saturated visible counter — further edits here
// require disasm evidence; do not re-blind-poke.
template <int IN, int OUT, int HEADS>
static __device__ void gemm_body(const float* __restrict__ x, const float* __restrict__ W,
                                 const float* __restrict__ asrc, const float* __restrict__ adst,
                                 unsigned short* __restrict__ h, float* __restrict__ als,
                                 float* __restrict__ ald, int bid) {
    constexpr int SPLIT = OUT / 16;            // col-slices (4 or 2)
    constexpr int NPB = 256 / SPLIT;           // rows per block: 64 (L1/L2) or 128 (L3)
    constexpr int KCH = 32;                    // k-chunk
    constexpr int KST = KCH + 1;               // padded stride: 33 -> conflict-free
    __shared__ alignas(16) float sx[NPB * KST];
    __shared__ alignas(16) float sw[KCH * OUT];
    int t = threadIdx.x;
    long base = (long)bid * NPB;

    int w = t >> 6, lane = t & 63;
    int s = __builtin_amdgcn_readfirstlane(w % SPLIT);
    int rg = __builtin_amdgcn_readfirstlane(w / SPLIT);
    int r = rg * 64 + lane;                    // SPLIT=4: rg=0, r=lane; SPLIT=2: r in 0..127
    long n = base + r;

    float acc[16];
#pragma unroll
    for (int j = 0; j < 16; ++j) acc[j] = 0.f;

    for (int k0 = 0; k0 < IN; k0 += KCH) {
        __syncthreads();                       // prior chunk fully consumed
        // stage x chunk: NPB rows x KCH floats (float4 granularity, 8 f4/row)
#pragma unroll
        for (int e = t; e < NPB * (KCH / 4); e += 256) {
            int row = e >> 3, c4 = e & 7;
            long gr = base + row;
            if (gr >= N_NODES) gr = N_NODES - 1;
            float4 v = *reinterpret_cast<const float4*>(&x[gr * IN + k0 + c4 * 4]);
            float* d = &sx[row * KST + c4 * 4];
            d[0] = v.x; d[1] = v.y; d[2] = v.z; d[3] = v.w;
        }
        // stage W chunk: KCH x OUT floats, fully coalesced
#pragma unroll
        for (int e = t; e < KCH * OUT / 4; e += 256)
            reinterpret_cast<float4*>(sw)[e] =
                reinterpret_cast<const float4*>(W + (long)k0 * OUT)[e];
        __syncthreads();                       // chunk ready

        const float* swb = sw + s * 16;
#pragma unroll 8
        for (int k = 0; k < KCH; ++k) {
            float xv = sx[r * KST + k];
            const float* Wr = swb + k * OUT;
#pragma unroll
            for (int j = 0; j < 16; ++j) acc[j] = fmaf(xv, Wr[j], acc[j]);
        }
    }

    if (n < N_NODES) {
        unsigned u[8];
#pragma unroll
        for (int k = 0; k < 8; ++k) u[k] = pack2h(acc[2 * k], acc[2 * k + 1]);
        uint4* dst = reinterpret_cast<uint4*>(&h[n * OUT + s * 16]);
        dst[0] = make_uint4(u[0], u[1], u[2], u[3]);
        dst[1] = make_uint4(u[4], u[5], u[6], u[7]);
    }

    float ps = 0.f, pd = 0.f;
#pragma unroll
    for (int j = 0; j < 16; ++j) {
        ps = fmaf(acc[j], asrc[s * 16 + j], ps);
        pd = fmaf(acc[j], adst[s * 16 + j], pd);
    }
    if (HEADS == SPLIT) {                      // layers 1-2: slice s IS head s
        if (n < N_NODES) {
            als[n * HEADS + s] = ps;
            ald[n * HEADS + s] = pd;
        }
    } else {                                   // layer 3: sum the SPLIT col-slices
        __syncthreads();
        sx[r * 2 + s] = ps;
        sx[NPB * 2 + r * 2 + s] = pd;
        __syncthreads();
        if (t < NPB) {
            long nn = base + t;
            if (nn < N_NODES) {
                als[nn] = sx[t * 2] + sx[t * 2 + 1];
                ald[nn] = sx[NPB * 2 + t * 2] + sx[NPB * 2 + t * 2 + 1];
            }
        }
    }
}

// ---------------- fused dispatch: layer-1 gemm || bucket build ----------------
__global__ __launch_bounds__(256, 8) void gemm1_build(const float* __restrict__ x, const float* __restrict__ W,
                                                      const float* __restrict__ asrc, const float* __restrict__ adst,
                                                      unsigned short* __restrict__ h, float* __restrict__ als,
                                                      float* __restrict__ ald, const int* __restrict__ ei,
                                                      int* __restrict__ tails, unsigned* __restrict__ stage) {
    if ((int)blockIdx.x < G64)
        gemm_body<128, 64, 4>(x, W, asrc, adst, h, als, ald, (int)blockIdx.x);
    else
        build_body((int)blockIdx.x - G64, ei, tails, stage);
}

// standalone gemm for layers 2-3
template <int IN, int OUT, int HEADS>
__global__ __launch_bounds__(256, 8) void gemm_al(const float* __restrict__ x, const float* __restrict__ W,
                                                  const float* __restrict__ asrc, const float* __restrict__ adst,
                                                  unsigned short* __restrict__ h, float* __restrict__ als,
                                                  float* __restrict__ ald) {
    gemm_body<IN, OUT, HEADS>(x, W, asrc, adst, h, als, ald, (int)blockIdx.x);
}

// ---------------- phase B: node-exclusive bucket assembly, LDS counters only ----------------
__global__ __launch_bounds__(1024) void bucket_fill(const int* __restrict__ tails, const unsigned* __restrict__ stage,
                                                    int* __restrict__ cnt, int* __restrict__ srcs) {
    __shared__ int lc[1 << BSH];
    int tid = threadIdx.x;
    int bin = blockIdx.x;
    int base = bin << BSH;
    int nn = N_NODES - base; if (nn > (1 << BSH)) nn = 1 << BSH;
    if (tid < nn) {
        lc[tid] = 1;                           // self-loop occupies slot 0
        srcs[(base + tid) * CAP] = base + tid;
    }
    __syncthreads();

    for (int st = 0; st < 8; ++st) {
        int len = tails[st * 128 + bin];
        if (len > SCAP2) len = SCAP2;
        const unsigned* sl = stage + ((((unsigned)bin << 3) | (unsigned)st) << SSH2);
        for (int i = tid; i < len; i += 1024) {
            unsigned v = __builtin_nontemporal_load(sl + i);
            int dloc = (int)(v >> 17);
            int s = (int)(v & 0x1FFFFu);
            int slot = atomicAdd(&lc[dloc], 1);
            if (slot < CAP) srcs[(base + dloc) * CAP + slot] = s;
        }
    }
    __syncthreads();
    if (tid < nn) cnt[base + tid] = lc[tid];   // agg clamps deg > CAP
}

// XCD-aligned node mapping for agg: XCD k (blockIdx&7) processes dst range k.
static __device__ __forceinline__ int agg_node(int blk, int wid) {
    return (blk & 7) * PART_SZ + (blk >> 3) * 4 + wid;
}

// ---------------- degree-adaptive straight-line bodies (round-23, validated) ----------------
template <int NG>
static __device__ __forceinline__ void agg4_run(
    int sl, int deg, int dm1, int q, int cc, int hd, float ad,
    const uint4* __restrict__ hrow, const float* __restrict__ als,
    float& a0, float& a1, float& a2, float& a3,
    float& a4, float& a5, float& a6, float& a7, float& den)
{
    int sv[NG]; float alv[NG]; uint4 hv[NG];
#pragma unroll
    for (int t = 0; t < NG; ++t) sv[t] = __shfl(sl, imin(t * 8 + q, dm1));
#pragma unroll
    for (int t = 0; t < NG; ++t) alv[t] = als[sv[t] * 4 + hd];
#pragma unroll
    for (int t = 0; t < NG; ++t) hv[t] = hrow[(long)sv[t] * 8 + cc];
    __builtin_amdgcn_sched_barrier(0);
#pragma unroll
    for (int t = 0; t < NG; ++t) {
        float w = (t * 8 + q) < deg ? __expf(lrelu(alv[t] + ad)) : 0.f;
        den += w;
        __half2 p0 = __builtin_bit_cast(__half2, hv[t].x);
        __half2 p1 = __builtin_bit_cast(__half2, hv[t].y);
        __half2 p2 = __builtin_bit_cast(__half2, hv[t].z);
        __half2 p3 = __builtin_bit_cast(__half2, hv[t].w);
        a0 = fmaf(w, (float)p0.x, a0); a1 = fmaf(w, (float)p0.y, a1);
        a2 = fmaf(w, (float)p1.x, a2); a3 = fmaf(w, (float)p1.y, a3);
        a4 = fmaf(w, (float)p2.x, a4); a5 = fmaf(w, (float)p2.y, a5);
        a6 = fmaf(w, (float)p3.x, a6); a7 = fmaf(w, (float)p3.y, a7);
    }
}

template <int NG>
static __device__ __forceinline__ void agg1_run(
    int sl, int deg, int dm1, int q, int cc, float ad,
    const uint4* __restrict__ hrow, const float* __restrict__ als,
    float& a0, float& a1, float& a2, float& a3,
    float& a4, float& a5, float& a6, float& a7, float& den)
{
    int sv[NG]; float alv[NG]; uint4 hv[NG];
#pragma unroll
    for (int t = 0; t < NG; ++t) sv[t] = __shfl(sl, imin(t * 16 + q, dm1));
#pragma unroll
    for (int t = 0; t < NG; ++t) alv[t] = als[sv[t]];
#pragma unroll
    for (int t = 0; t < NG; ++t) hv[t] = hrow[(long)sv[t] * 4 + cc];
    __builtin_amdgcn_sched_barrier(0);
#pragma unroll
    for (int t = 0; t < NG; ++t) {
        float w = (t * 16 + q) < deg ? __expf(lrelu(alv[t] + ad)) : 0.f;
        den += w;
        __half2 p0 = __builtin_bit_cast(__half2, hv[t].x);
        __half2 p1 = __builtin_bit_cast(__half2, hv[t].y);
        __half2 p2 = __builtin_bit_cast(__half2, hv[t].z);
        __half2 p3 = __builtin_bit_cast(__half2, hv[t].w);
        a0 = fmaf(w, (float)p0.x, a0); a1 = fmaf(w, (float)p0.y, a1);
        a2 = fmaf(w, (float)p1.x, a2); a3 = fmaf(w, (float)p1.y, a3);
        a4 = fmaf(w, (float)p2.x, a4); a5 = fmaf(w, (float)p2.y, a5);
        a6 = fmaf(w, (float)p3.x, a6); a7 = fmaf(w, (float)p3.y, a7);
    }
}

// ---------------- aggregation, H=4 C=16, fp16 payload, uint4 lanes ----------------
__global__ __launch_bounds__(256, 8) void agg_h4(const int* __restrict__ cnt, const int* __restrict__ srcs,
                                                 const unsigned short* __restrict__ h, const float* __restrict__ als,
                                                 const float* __restrict__ ald, const float* __restrict__ bias,
                                                 float* __restrict__ g, int do_relu) {
    const uint4* hrow = reinterpret_cast<const uint4*>(h);   // 8 uint4 per 64-ch row
    int wid = threadIdx.x >> 6, lane = threadIdx.x & 63;
    int n = agg_node(blockIdx.x, wid);
    if (n >= N_NODES) return;
    int q = lane >> 3, cc = lane & 7;
    int hd = cc >> 1;
    float ad = ald[n * 4 + hd];
    int deg = cnt[n]; if (deg > CAP) deg = CAP;   // deg >= 1 (self-loop), wave-uniform
    int dm1 = deg - 1;
    int sl = srcs[n * CAP + imin(lane, dm1)];     // whole bucket, one coalesced load

    float a0 = 0.f, a1 = 0.f, a2 = 0.f, a3 = 0.f, a4 = 0.f, a5 = 0.f, a6 = 0.f, a7 = 0.f;
    float den = 0.f;

    switch ((deg + 7) >> 3) {                     // wave-uniform scalar dispatch
    case 1: agg4_run<1>(sl, deg, dm1, q, cc, hd, ad, hrow, als, a0, a1, a2, a3, a4, a5, a6, a7, den); break;
    case 2: agg4_run<2>(sl, deg, dm1, q, cc, hd, ad, hrow, als, a0, a1, a2, a3, a4, a5, a6, a7, den); break;
    case 3: agg4_run<3>(sl, deg, dm1, q, cc, hd, ad, hrow, als, a0, a1, a2, a3, a4, a5, a6, a7, den); break;
    default:
        agg4_run<4>(sl, deg, dm1, q, cc, hd, ad, hrow, als, a0, a1, a2, a3, a4, a5, a6, a7, den);
        if (__builtin_expect(deg > 32, 0)) {      // wave-uniform rare tail
            for (int e = 32; e < deg; e += 8) {
                int ee = e + q;
                int s = __shfl(sl, imin(ee, dm1));
                float al = als[s * 4 + hd];
                uint4 hv = hrow[(long)s * 8 + cc];
                float w = ee < deg ? __expf(lrelu(al + ad)) : 0.f;
                den += w;
                __half2 p0 = __builtin_bit_cast(__half2, hv.x);
                __half2 p1 = __builtin_bit_cast(__half2, hv.y);
                __half2 p2 = __builtin_bit_cast(__half2, hv.z);
                __half2 p3 = __builtin_bit_cast(__half2, hv.w);
                a0 = fmaf(w, (float)p0.x, a0); a1 = fmaf(w, (float)p0.y, a1);
                a2 = fmaf(w, (float)p1.x, a2); a3 = fmaf(w, (float)p1.y, a3);
                a4 = fmaf(w, (float)p2.x, a4); a5 = fmaf(w, (float)p2.y, a5);
                a6 = fmaf(w, (float)p3.x, a6); a7 = fmaf(w, (float)p3.y, a7);
            }
        }
        break;
    }

#pragma unroll
    for (int d = 8; d <= 32; d <<= 1) {
        a0 += __shfl_xor(a0, d); a1 += __shfl_xor(a1, d);
        a2 += __shfl_xor(a2, d); a3 += __shfl_xor(a3, d);
        a4 += __shfl_xor(a4, d); a5 += __shfl_xor(a5, d);
        a6 += __shfl_xor(a6, d); a7 += __shfl_xor(a7, d);
        den += __shfl_xor(den, d);
    }
    if (q == 0) {
        float4 b0 = *reinterpret_cast<const float4*>(&bias[cc * 8]);
        float4 b1 = *reinterpret_cast<const float4*>(&bias[cc * 8 + 4]);
        float inv = 1.f / den;
        float4 o0, o1;
        o0.x = fmaf(a0, inv, b0.x); o0.y = fmaf(a1, inv, b0.y);
        o0.z = fmaf(a2, inv, b0.z); o0.w = fmaf(a3, inv, b0.w);
        o1.x = fmaf(a4, inv, b1.x); o1.y = fmaf(a5, inv, b1.y);
        o1.z = fmaf(a6, inv, b1.z); o1.w = fmaf(a7, inv, b1.w);
        if (do_relu) {
            o0.x = fmaxf(o0.x, 0.f); o0.y = fmaxf(o0.y, 0.f);
            o0.z = fmaxf(o0.z, 0.f); o0.w = fmaxf(o0.w, 0.f);
            o1.x = fmaxf(o1.x, 0.f); o1.y = fmaxf(o1.y, 0.f);
            o1.z = fmaxf(o1.z, 0.f); o1.w = fmaxf(o1.w, 0.f);
        }
        *reinterpret_cast<float4*>(&g[(long)n * 64 + cc * 8]) = o0;
        *reinterpret_cast<float4*>(&g[(long)n * 64 + cc * 8 + 4]) = o1;
    }
}

// ---------------- aggregation, H=1 C=32, fp16 payload, uint4 lanes ----------------
__global__ __launch_bounds__(256, 8) void agg_h1(const int* __restrict__ cnt, const int* __restrict__ srcs,
                                                 const unsigned short* __restrict__ h3, const float* __restrict__ als,
                                                 const float* __restrict__ ald, const float* __restrict__ bias,
                                                 float* __restrict__ out) {
    const uint4* hrow = reinterpret_cast<const uint4*>(h3);  // 4 uint4 per 32-ch row
    int wid = threadIdx.x >> 6, lane = threadIdx.x & 63;
    int n = agg_node(blockIdx.x, wid);
    if (n >= N_NODES) return;
    int q = lane >> 2, cc = lane & 3;
    float ad = ald[n];
    int deg = cnt[n]; if (deg > CAP) deg = CAP;
    int dm1 = deg - 1;
    int sl = srcs[n * CAP + imin(lane, dm1)];

    float a0 = 0.f, a1 = 0.f, a2 = 0.f, a3 = 0.f, a4 = 0.f, a5 = 0.f, a6 = 0.f, a7 = 0.f;
    float den = 0.f;

    switch ((deg + 15) >> 4) {                    // wave-uniform scalar dispatch
    case 1: agg1_run<1>(sl, deg, dm1, q, cc, ad, hrow, als, a0, a1, a2, a3, a4, a5, a6, a7, den); break;
    case 2: agg1_run<2>(sl, deg, dm1, q, cc, ad, hrow, als, a0, a1, a2, a3, a4, a5, a6, a7, den); break;
    default: agg1_run<3>(sl, deg, dm1, q, cc, ad, hrow, als, a0, a1, a2, a3, a4, a5, a6, a7, den); break;
    }

#pragma unroll
    for (int d = 4; d <= 32; d <<= 1) {
        a0 += __shfl_xor(a0, d); a1 += __shfl_xor(a1, d);
        a2 += __shfl_xor(a2, d); a3 += __shfl_xor(a3, d);
        a4 += __shfl_xor(a4, d); a5 += __shfl_xor(a5, d);
        a6 += __shfl_xor(a6, d); a7 += __shfl_xor(a7, d);
        den += __shfl_xor(den, d);
    }
    if (q == 0) {
        float4 b0 = *reinterpret_cast<const float4*>(&bias[cc * 8]);
        float4 b1 = *reinterpret_cast<const float4*>(&bias[cc * 8 + 4]);
        float inv = 1.f / den;
        float4 o0, o1;
        o0.x = fmaf(a0, inv, b0.x); o0.y = fmaf(a1, inv, b0.y);
        o0.z = fmaf(a2, inv, b0.z); o0.w = fmaf(a3, inv, b0.w);
        o1.x = fmaf(a4, inv, b1.x); o1.y = fmaf(a5, inv, b1.y);
        o1.z = fmaf(a6, inv, b1.z); o1.w = fmaf(a7, inv, b1.w);
        *reinterpret_cast<float4*>(&out[(long)n * 32 + cc * 8]) = o0;
        *reinterpret_cast<float4*>(&out[(long)n * 32 + cc * 8 + 4]) = o1;
    }
}

extern "C" void kernel_launch(void* const* d_in, const int* in_sizes, int n_in,
                              void* d_out, int out_size, void* d_ws, size_t ws_size,
                              hipStream_t stream) {
    (void)in_sizes; (void)n_in; (void)out_size; (void)ws_size;
    const float* x   = (const float*)d_in[0];
    const int*   ei  = (const int*)d_in[1];
    const float* W1  = (const float*)d_in[2];
    const float* as1 = (const float*)d_in[3];
    const float* ad1 = (const float*)d_in[4];
    const float* b1  = (const float*)d_in[5];
    const float* W2  = (const float*)d_in[6];
    const float* as2 = (const float*)d_in[7];
    const float* ad2 = (const float*)d_in[8];
    const float* b2  = (const float*)d_in[9];
    const float* W3  = (const float*)d_in[10];
    const float* as3 = (const float*)d_in[11];
    const float* ad3 = (const float*)d_in[12];
    const float* b3  = (const float*)d_in[13];
    float* out = (float*)d_out;

    char* w = (char*)d_ws;
    auto alloc = [&](size_t bytes) {
        void* p = (void*)w;
        w += (bytes + 255) & ~(size_t)255;
        return p;
    };
    int*            cnt   = (int*)alloc((size_t)N_NODES * 4);
    int*            tails = (int*)alloc((size_t)1024 * 4);            // 8 stripes x 128-int pad
    int*            srcs  = (int*)alloc((size_t)N_NODES * CAP * 4);   // 19.2 MB
    unsigned short* h     = (unsigned short*)alloc((size_t)N_NODES * 64 * 2);  // fp16, 12.8 MB
    float*          g     = (float*)alloc((size_t)N_NODES * 64 * 4);  // 25.6 MB
    float*          als   = (float*)alloc((size_t)N_NODES * 4 * 4);
    float*          ald   = (float*)alloc((size_t)N_NODES * 4 * 4);
    // staging (12.85 MB) aliases g: consumed by bucket_fill before agg_h4 first writes g.
    unsigned*       stage = (unsigned*)g;

    hipMemsetAsync(tails, 0, (size_t)1024 * 4, stream);   // cnt memset not needed

    int g64  = G64;                    // 1563 (layers 1-2: NPB=64)
    int g128 = (N_NODES + 127) / 128;  // 782  (layer 3:   NPB=128)
    int gAgg = ((N_NODES + 3) / 4 + 7) & ~7;   // 25000 -> mult of 8

    // layer 1 gemm || bucket build (independent: x/W1 vs ei) in one dispatch
    gemm1_build<<<G64 + GBUILD, 256, 0, stream>>>(x, W1, as1, ad1, h, als, ald, ei, tails, stage);
    bucket_fill<<<NBIN, 1024, 0, stream>>>(tails, stage, cnt, srcs);

    agg_h4<<<gAgg, 256, 0, stream>>>(cnt, srcs, h, als, ald, b1, g, 1);
    // layer 2: g[100000,64] @ W2[64,64], H=4
    gemm_al<64, 64, 4><<<g64, 256, 0, stream>>>(g, W2, as2, ad2, h, als, ald);
    agg_h4<<<gAgg, 256, 0, stream>>>(cnt, srcs, h, als, ald, b2, g, 1);
    // layer 3: g[100000,64] @ W3[64,32], H=1 -> d_out
    gemm_al<64, 32, 1><<<g128, 256, 0, stream>>>(g, W3, as3, ad3, h, als, ald);
    agg_h1<<<gAgg, 256, 0, stream>>>(cnt, srcs, h, als, ald, b3, out);
}

// Round 16
// 318.535 us; speedup vs baseline: 1.1292x; 1.0595x over previous
//
#include <hip/hip_runtime.h>
#include <hip/hip_fp16.h>

#define N_NODES 100000
#define N_EDGES 1600000
#define NPART   8
#define PART_SZ (N_NODES / NPART)   // 12500 (agg node mapping)
#define CAP 48                      // bucket capacity; degree ~ Poisson(16), P(>=48) ~ 1e-9
#define BSH  10                     // nodes per fill bin = 1024 (node-exclusive block ownership)
#define NBIN 98                     // ceil(100000 / 1024)
#define SCAP2 4096                  // per-(bin,stripe) staging cap: mean 2048, sigma 45 -> +45 sigma
#define SSH2 12                     // log2(SCAP2)
#define EPB  2048                   // edges per build block
#define G64  ((N_NODES + 63) / 64)  // 1563: gemm-role blocks in the fused dispatch
#define GBUILD ((N_EDGES + EPB - 1) / EPB)  // 782: build-role blocks

static __device__ __forceinline__ float lrelu(float z) { return z > 0.f ? z : 0.2f * z; }
static __device__ __forceinline__ int imin(int a, int b) { return a < b ? a : b; }

// pack two floats into one u32 of fp16 pair (h payload is fp16 since round-9)
static __device__ __forceinline__ unsigned pack2h(float a, float b) {
    return __builtin_bit_cast(unsigned, __floats2half2_rn(a, b));
}

// ---------------- build body: single-pass edge binning at 1024-node granularity ----------------
// (round-15: validated; round-24: fused into the layer-1 gemm dispatch — validated, build
// overlaps under gemm stalls for ~4 us net cost.)
static __device__ void build_body(int bid, const int* __restrict__ ei, int* __restrict__ tails,
                                  unsigned* __restrict__ stage) {
    __shared__ int lcnt[NBIN];
    __shared__ int lbase[NBIN];
    int tid = threadIdx.x;
    if (tid < NBIN) lcnt[tid] = 0;
    __syncthreads();

    int stripe = bid & 7;
    int e0 = bid * EPB;
    int binv[EPB / 256];
    int slotv[EPB / 256];
    unsigned vv[EPB / 256];
#pragma unroll
    for (int k = 0; k < EPB / 256; ++k) {
        int t = e0 + k * 256 + tid;
        binv[k] = -1;
        if (t < N_EDGES) {
            int d = __builtin_nontemporal_load(ei + N_EDGES + t);
            int s = __builtin_nontemporal_load(ei + t);
            int b = d >> BSH;
            vv[k] = ((unsigned)(d & ((1 << BSH) - 1)) << 17) | (unsigned)s;  // dloc 10b | src 17b
            slotv[k] = atomicAdd(&lcnt[b], 1);
            binv[k] = b;
        }
    }
    __syncthreads();

    if (tid < NBIN) lbase[tid] = atomicAdd(&tails[stripe * 128 + tid], lcnt[tid]);
    __syncthreads();

#pragma unroll
    for (int k = 0; k < EPB / 256; ++k) {
        if (binv[k] >= 0) {
            int pos = lbase[binv[k]] + slotv[k];
            if (pos < SCAP2)
                stage[((((unsigned)binv[k] << 3) | (unsigned)stripe) << SSH2) + (unsigned)pos] = vv[k];
        }
    }
}

// ---------------- gemm body: x in LDS, W in SGPRs via 4-k burst s_loads ----------------
// Round-25: occupancy series 17.6->50% left duration pinned at ~50-54 us, VALU 22-24% —
// not latency, not VALU, not HBM. LDS-pipe arithmetic (m134): W broadcast reads =
// 6.1 blk x 4 wv x 128 k x 4 ds_read_b128 ~ 150K cy/CU ~ 62 us — matches. (Round-11's
// "refutation" was occupancy-confounded.) Fix: W is WAVE-UNIFORM -> belongs in SMEM/
// SGPRs. Round-8's per-k s_load failed on per-k DS<->SMEM lgkmcnt drains (SMEM is OOO);
// here W loads come in 4-k bursts (64-float uniform array -> s_load_dwordx8/16), x loads
// for the 4 k issued alongside, ONE drain per chunk (amortized 4x), sched_barrier(0)
// pins load-cluster before FMA-cluster while letting chunk c+1 loads overlap chunk c
// FMAs. sw LDS staging deleted (W served from L2/sK$) -> LDS 8.4 KB.
template <int IN, int OUT, int HEADS>
static __device__ void gemm_body(const float* __restrict__ x, const float* __restrict__ W,
                                 const float* __restrict__ asrc, const float* __restrict__ adst,
                                 unsigned short* __restrict__ h, float* __restrict__ als,
                                 float* __restrict__ ald, int bid) {
    constexpr int SPLIT = OUT / 16;            // col-slices (4 or 2)
    constexpr int NPB = 256 / SPLIT;           // rows per block: 64 (L1/L2) or 128 (L3)
    constexpr int KCH = 32;                    // k-window staged in LDS
    constexpr int KST = KCH + 1;               // padded stride: 33 -> conflict-free b32
    __shared__ alignas(16) float sx[NPB * KST];
    int t = threadIdx.x;
    long base = (long)bid * NPB;

    int w = t >> 6, lane = t & 63;
    int s = __builtin_amdgcn_readfirstlane(w % SPLIT);
    int rg = __builtin_amdgcn_readfirstlane(w / SPLIT);
    int r = rg * 64 + lane;                    // SPLIT=4: rg=0, r=lane; SPLIT=2: r in 0..127
    long n = base + r;

    float acc[16];
#pragma unroll
    for (int j = 0; j < 16; ++j) acc[j] = 0.f;

    for (int k0 = 0; k0 < IN; k0 += KCH) {
        __syncthreads();                       // prior window fully consumed
        // stage x window: NPB rows x KCH floats (float4 granularity, 8 f4/row)
#pragma unroll
        for (int e = t; e < NPB * (KCH / 4); e += 256) {
            int row = e >> 3, c4 = e & 7;
            long gr = base + row;
            if (gr >= N_NODES) gr = N_NODES - 1;
            float4 v = *reinterpret_cast<const float4*>(&x[gr * IN + k0 + c4 * 4]);
            float* d = &sx[row * KST + c4 * 4];
            d[0] = v.x; d[1] = v.y; d[2] = v.z; d[3] = v.w;
        }
        __syncthreads();                       // window ready

        const float* Wk = W + (long)k0 * OUT + s * 16;   // uniform base -> s_load path
#pragma unroll
        for (int kc = 0; kc < KCH; kc += 4) {
            float wv[4][16];                   // wave-uniform -> SGPRs (burst s_loads)
#pragma unroll
            for (int kk = 0; kk < 4; ++kk)
#pragma unroll
                for (int j = 0; j < 16; ++j)
                    wv[kk][j] = Wk[(kc + kk) * OUT + j];
            float xv[4];
#pragma unroll
            for (int kk = 0; kk < 4; ++kk) xv[kk] = sx[r * KST + kc + kk];
            __builtin_amdgcn_sched_barrier(0); // loads issued; one drain, then pure FMA
#pragma unroll
            for (int kk = 0; kk < 4; ++kk)
#pragma unroll
                for (int j = 0; j < 16; ++j)
                    acc[j] = fmaf(xv[kk], wv[kk][j], acc[j]);
        }
    }

    if (n < N_NODES) {
        unsigned u[8];
#pragma unroll
        for (int k = 0; k < 8; ++k) u[k] = pack2h(acc[2 * k], acc[2 * k + 1]);
        uint4* dst = reinterpret_cast<uint4*>(&h[n * OUT + s * 16]);
        dst[0] = make_uint4(u[0], u[1], u[2], u[3]);
        dst[1] = make_uint4(u[4], u[5], u[6], u[7]);
    }

    float ps = 0.f, pd = 0.f;
#pragma unroll
    for (int j = 0; j < 16; ++j) {
        ps = fmaf(acc[j], asrc[s * 16 + j], ps);
        pd = fmaf(acc[j], adst[s * 16 + j], pd);
    }
    if (HEADS == SPLIT) {                      // layers 1-2: slice s IS head s
        if (n < N_NODES) {
            als[n * HEADS + s] = ps;
            ald[n * HEADS + s] = pd;
        }
    } else {                                   // layer 3: sum the SPLIT col-slices
        __syncthreads();
        sx[r * 2 + s] = ps;
        sx[NPB * 2 + r * 2 + s] = pd;
        __syncthreads();
        if (t < NPB) {
            long nn = base + t;
            if (nn < N_NODES) {
                als[nn] = sx[t * 2] + sx[t * 2 + 1];
                ald[nn] = sx[NPB * 2 + t * 2] + sx[NPB * 2 + t * 2 + 1];
            }
        }
    }
}

// ---------------- fused dispatch: layer-1 gemm || bucket build ----------------
__global__ __launch_bounds__(256, 8) void gemm1_build(const float* __restrict__ x, const float* __restrict__ W,
                                                      const float* __restrict__ asrc, const float* __restrict__ adst,
                                                      unsigned short* __restrict__ h, float* __restrict__ als,
                                                      float* __restrict__ ald, const int* __restrict__ ei,
                                                      int* __restrict__ tails, unsigned* __restrict__ stage) {
    if ((int)blockIdx.x < G64)
        gemm_body<128, 64, 4>(x, W, asrc, adst, h, als, ald, (int)blockIdx.x);
    else
        build_body((int)blockIdx.x - G64, ei, tails, stage);
}

// standalone gemm for layers 2-3
template <int IN, int OUT, int HEADS>
__global__ __launch_bounds__(256, 8) void gemm_al(const float* __restrict__ x, const float* __restrict__ W,
                                                  const float* __restrict__ asrc, const float* __restrict__ adst,
                                                  unsigned short* __restrict__ h, float* __restrict__ als,
                                                  float* __restrict__ ald) {
    gemm_body<IN, OUT, HEADS>(x, W, asrc, adst, h, als, ald, (int)blockIdx.x);
}

// ---------------- phase B: node-exclusive bucket assembly, LDS counters only ----------------
__global__ __launch_bounds__(1024) void bucket_fill(const int* __restrict__ tails, const unsigned* __restrict__ stage,
                                                    int* __restrict__ cnt, int* __restrict__ srcs) {
    __shared__ int lc[1 << BSH];
    int tid = threadIdx.x;
    int bin = blockIdx.x;
    int base = bin << BSH;
    int nn = N_NODES - base; if (nn > (1 << BSH)) nn = 1 << BSH;
    if (tid < nn) {
        lc[tid] = 1;                           // self-loop occupies slot 0
        srcs[(base + tid) * CAP] = base + tid;
    }
    __syncthreads();

    for (int st = 0; st < 8; ++st) {
        int len = tails[st * 128 + bin];
        if (len > SCAP2) len = SCAP2;
        const unsigned* sl = stage + ((((unsigned)bin << 3) | (unsigned)st) << SSH2);
        for (int i = tid; i < len; i += 1024) {
            unsigned v = __builtin_nontemporal_load(sl + i);
            int dloc = (int)(v >> 17);
            int s = (int)(v & 0x1FFFFu);
            int slot = atomicAdd(&lc[dloc], 1);
            if (slot < CAP) srcs[(base + dloc) * CAP + slot] = s;
        }
    }
    __syncthreads();
    if (tid < nn) cnt[base + tid] = lc[tid];   // agg clamps deg > CAP
}

// XCD-aligned node mapping for agg: XCD k (blockIdx&7) processes dst range k.
static __device__ __forceinline__ int agg_node(int blk, int wid) {
    return (blk & 7) * PART_SZ + (blk >> 3) * 4 + wid;
}

// ---------------- degree-adaptive straight-line bodies (round-23, validated) ----------------
template <int NG>
static __device__ __forceinline__ void agg4_run(
    int sl, int deg, int dm1, int q, int cc, int hd, float ad,
    const uint4* __restrict__ hrow, const float* __restrict__ als,
    float& a0, float& a1, float& a2, float& a3,
    float& a4, float& a5, float& a6, float& a7, float& den)
{
    int sv[NG]; float alv[NG]; uint4 hv[NG];
#pragma unroll
    for (int t = 0; t < NG; ++t) sv[t] = __shfl(sl, imin(t * 8 + q, dm1));
#pragma unroll
    for (int t = 0; t < NG; ++t) alv[t] = als[sv[t] * 4 + hd];
#pragma unroll
    for (int t = 0; t < NG; ++t) hv[t] = hrow[(long)sv[t] * 8 + cc];
    __builtin_amdgcn_sched_barrier(0);
#pragma unroll
    for (int t = 0; t < NG; ++t) {
        float w = (t * 8 + q) < deg ? __expf(lrelu(alv[t] + ad)) : 0.f;
        den += w;
        __half2 p0 = __builtin_bit_cast(__half2, hv[t].x);
        __half2 p1 = __builtin_bit_cast(__half2, hv[t].y);
        __half2 p2 = __builtin_bit_cast(__half2, hv[t].z);
        __half2 p3 = __builtin_bit_cast(__half2, hv[t].w);
        a0 = fmaf(w, (float)p0.x, a0); a1 = fmaf(w, (float)p0.y, a1);
        a2 = fmaf(w, (float)p1.x, a2); a3 = fmaf(w, (float)p1.y, a3);
        a4 = fmaf(w, (float)p2.x, a4); a5 = fmaf(w, (float)p2.y, a5);
        a6 = fmaf(w, (float)p3.x, a6); a7 = fmaf(w, (float)p3.y, a7);
    }
}

template <int NG>
static __device__ __forceinline__ void agg1_run(
    int sl, int deg, int dm1, int q, int cc, float ad,
    const uint4* __restrict__ hrow, const float* __restrict__ als,
    float& a0, float& a1, float& a2, float& a3,
    float& a4, float& a5, float& a6, float& a7, float& den)
{
    int sv[NG]; float alv[NG]; uint4 hv[NG];
#pragma unroll
    for (int t = 0; t < NG; ++t) sv[t] = __shfl(sl, imin(t * 16 + q, dm1));
#pragma unroll
    for (int t = 0; t < NG; ++t) alv[t] = als[sv[t]];
#pragma unroll
    for (int t = 0; t < NG; ++t) hv[t] = hrow[(long)sv[t] * 4 + cc];
    __builtin_amdgcn_sched_barrier(0);
#pragma unroll
    for (int t = 0; t < NG; ++t) {
        float w = (t * 16 + q) < deg ? __expf(lrelu(alv[t] + ad)) : 0.f;
        den += w;
        __half2 p0 = __builtin_bit_cast(__half2, hv[t].x);
        __half2 p1 = __builtin_bit_cast(__half2, hv[t].y);
        __half2 p2 = __builtin_bit_cast(__half2, hv[t].z);
        __half2 p3 = __builtin_bit_cast(__half2, hv[t].w);
        a0 = fmaf(w, (float)p0.x, a0); a1 = fmaf(w, (float)p0.y, a1);
        a2 = fmaf(w, (float)p1.x, a2); a3 = fmaf(w, (float)p1.y, a3);
        a4 = fmaf(w, (float)p2.x, a4); a5 = fmaf(w, (float)p2.y, a5);
        a6 = fmaf(w, (float)p3.x, a6); a7 = fmaf(w, (float)p3.y, a7);
    }
}

// ---------------- aggregation, H=4 C=16, fp16 payload, uint4 lanes ----------------
__global__ __launch_bounds__(256, 8) void agg_h4(const int* __restrict__ cnt, const int* __restrict__ srcs,
                                                 const unsigned short* __restrict__ h, const float* __restrict__ als,
                                                 const float* __restrict__ ald, const float* __restrict__ bias,
                                                 float* __restrict__ g, int do_relu) {
    const uint4* hrow = reinterpret_cast<const uint4*>(h);   // 8 uint4 per 64-ch row
    int wid = threadIdx.x >> 6, lane = threadIdx.x & 63;
    int n = agg_node(blockIdx.x, wid);
    if (n >= N_NODES) return;
    int q = lane >> 3, cc = lane & 7;
    int hd = cc >> 1;
    float ad = ald[n * 4 + hd];
    int deg = cnt[n]; if (deg > CAP) deg = CAP;   // deg >= 1 (self-loop), wave-uniform
    int dm1 = deg - 1;
    int sl = srcs[n * CAP + imin(lane, dm1)];     // whole bucket, one coalesced load

    float a0 = 0.f, a1 = 0.f, a2 = 0.f, a3 = 0.f, a4 = 0.f, a5 = 0.f, a6 = 0.f, a7 = 0.f;
    float den = 0.f;

    switch ((deg + 7) >> 3) {                     // wave-uniform scalar dispatch
    case 1: agg4_run<1>(sl, deg, dm1, q, cc, hd, ad, hrow, als, a0, a1, a2, a3, a4, a5, a6, a7, den); break;
    case 2: agg4_run<2>(sl, deg, dm1, q, cc, hd, ad, hrow, als, a0, a1, a2, a3, a4, a5, a6, a7, den); break;
    case 3: agg4_run<3>(sl, deg, dm1, q, cc, hd, ad, hrow, als, a0, a1, a2, a3, a4, a5, a6, a7, den); break;
    default:
        agg4_run<4>(sl, deg, dm1, q, cc, hd, ad, hrow, als, a0, a1, a2, a3, a4, a5, a6, a7, den);
        if (__builtin_expect(deg > 32, 0)) {      // wave-uniform rare tail
            for (int e = 32; e < deg; e += 8) {
                int ee = e + q;
                int s = __shfl(sl, imin(ee, dm1));
                float al = als[s * 4 + hd];
                uint4 hv = hrow[(long)s * 8 + cc];
                float w = ee < deg ? __expf(lrelu(al + ad)) : 0.f;
                den += w;
                __half2 p0 = __builtin_bit_cast(__half2, hv.x);
                __half2 p1 = __builtin_bit_cast(__half2, hv.y);
                __half2 p2 = __builtin_bit_cast(__half2, hv.z);
                __half2 p3 = __builtin_bit_cast(__half2, hv.w);
                a0 = fmaf(w, (float)p0.x, a0); a1 = fmaf(w, (float)p0.y, a1);
                a2 = fmaf(w, (float)p1.x, a2); a3 = fmaf(w, (float)p1.y, a3);
                a4 = fmaf(w, (float)p2.x, a4); a5 = fmaf(w, (float)p2.y, a5);
                a6 = fmaf(w, (float)p3.x, a6); a7 = fmaf(w, (float)p3.y, a7);
            }
        }
        break;
    }

#pragma unroll
    for (int d = 8; d <= 32; d <<= 1) {
        a0 += __shfl_xor(a0, d); a1 += __shfl_xor(a1, d);
        a2 += __shfl_xor(a2, d); a3 += __shfl_xor(a3, d);
        a4 += __shfl_xor(a4, d); a5 += __shfl_xor(a5, d);
        a6 += __shfl_xor(a6, d); a7 += __shfl_xor(a7, d);
        den += __shfl_xor(den, d);
    }
    if (q == 0) {
        float4 b0 = *reinterpret_cast<const float4*>(&bias[cc * 8]);
        float4 b1 = *reinterpret_cast<const float4*>(&bias[cc * 8 + 4]);
        float inv = 1.f / den;
        float4 o0, o1;
        o0.x = fmaf(a0, inv, b0.x); o0.y = fmaf(a1, inv, b0.y);
        o0.z = fmaf(a2, inv, b0.z); o0.w = fmaf(a3, inv, b0.w);
        o1.x = fmaf(a4, inv, b1.x); o1.y = fmaf(a5, inv, b1.y);
        o1.z = fmaf(a6, inv, b1.z); o1.w = fmaf(a7, inv, b1.w);
        if (do_relu) {
            o0.x = fmaxf(o0.x, 0.f); o0.y = fmaxf(o0.y, 0.f);
            o0.z = fmaxf(o0.z, 0.f); o0.w = fmaxf(o0.w, 0.f);
            o1.x = fmaxf(o1.x, 0.f); o1.y = fmaxf(o1.y, 0.f);
            o1.z = fmaxf(o1.z, 0.f); o1.w = fmaxf(o1.w, 0.f);
        }
        *reinterpret_cast<float4*>(&g[(long)n * 64 + cc * 8]) = o0;
        *reinterpret_cast<float4*>(&g[(long)n * 64 + cc * 8 + 4]) = o1;
    }
}

// ---------------- aggregation, H=1 C=32, fp16 payload, uint4 lanes ----------------
__global__ __launch_bounds__(256, 8) void agg_h1(const int* __restrict__ cnt, const int* __restrict__ srcs,
                                                 const unsigned short* __restrict__ h3, const float* __restrict__ als,
                                                 const float* __restrict__ ald, const float* __restrict__ bias,
                                                 float* __restrict__ out) {
    const uint4* hrow = reinterpret_cast<const uint4*>(h3);  // 4 uint4 per 32-ch row
    int wid = threadIdx.x >> 6, lane = threadIdx.x & 63;
    int n = agg_node(blockIdx.x, wid);
    if (n >= N_NODES) return;
    int q = lane >> 2, cc = lane & 3;
    float ad = ald[n];
    int deg = cnt[n]; if (deg > CAP) deg = CAP;
    int dm1 = deg - 1;
    int sl = srcs[n * CAP + imin(lane, dm1)];

    float a0 = 0.f, a1 = 0.f, a2 = 0.f, a3 = 0.f, a4 = 0.f, a5 = 0.f, a6 = 0.f, a7 = 0.f;
    float den = 0.f;

    switch ((deg + 15) >> 4) {                    // wave-uniform scalar dispatch
    case 1: agg1_run<1>(sl, deg, dm1, q, cc, ad, hrow, als, a0, a1, a2, a3, a4, a5, a6, a7, den); break;
    case 2: agg1_run<2>(sl, deg, dm1, q, cc, ad, hrow, als, a0, a1, a2, a3, a4, a5, a6, a7, den); break;
    default: agg1_run<3>(sl, deg, dm1, q, cc, ad, hrow, als, a0, a1, a2, a3, a4, a5, a6, a7, den); break;
    }

#pragma unroll
    for (int d = 4; d <= 32; d <<= 1) {
        a0 += __shfl_xor(a0, d); a1 += __shfl_xor(a1, d);
        a2 += __shfl_xor(a2, d); a3 += __shfl_xor(a3, d);
        a4 += __shfl_xor(a4, d); a5 += __shfl_xor(a5, d);
        a6 += __shfl_xor(a6, d); a7 += __shfl_xor(a7, d);
        den += __shfl_xor(den, d);
    }
    if (q == 0) {
        float4 b0 = *reinterpret_cast<const float4*>(&bias[cc * 8]);
        float4 b1 = *reinterpret_cast<const float4*>(&bias[cc * 8 + 4]);
        float inv = 1.f / den;
        float4 o0, o1;
        o0.x = fmaf(a0, inv, b0.x); o0.y = fmaf(a1, inv, b0.y);
        o0.z = fmaf(a2, inv, b0.z); o0.w = fmaf(a3, inv, b0.w);
        o1.x = fmaf(a4, inv, b1.x); o1.y = fmaf(a5, inv, b1.y);
        o1.z = fmaf(a6, inv, b1.z); o1.w = fmaf(a7, inv, b1.w);
        *reinterpret_cast<float4*>(&out[(long)n * 32 + cc * 8]) = o0;
        *reinterpret_cast<float4*>(&out[(long)n * 32 + cc * 8 + 4]) = o1;
    }
}

extern "C" void kernel_launch(void* const* d_in, const int* in_sizes, int n_in,
                              void* d_out, int out_size, void* d_ws, size_t ws_size,
                              hipStream_t stream) {
    (void)in_sizes; (void)n_in; (void)out_size; (void)ws_size;
    const float* x   = (const float*)d_in[0];
    const int*   ei  = (const int*)d_in[1];
    const float* W1  = (const float*)d_in[2];
    const float* as1 = (const float*)d_in[3];
    const float* ad1 = (const float*)d_in[4];
    const float* b1  = (const float*)d_in[5];
    const float* W2  = (const float*)d_in[6];
    const float* as2 = (const float*)d_in[7];
    const float* ad2 = (const float*)d_in[8];
    const float* b2  = (const float*)d_in[9];
    const float* W3  = (const float*)d_in[10];
    const float* as3 = (const float*)d_in[11];
    const float* ad3 = (const float*)d_in[12];
    const float* b3  = (const float*)d_in[13];
    float* out = (float*)d_out;

    char* w = (char*)d_ws;
    auto alloc = [&](size_t bytes) {
        void* p = (void*)w;
        w += (bytes + 255) & ~(size_t)255;
        return p;
    };
    int*            cnt   = (int*)alloc((size_t)N_NODES * 4);
    int*            tails = (int*)alloc((size_t)1024 * 4);            // 8 stripes x 128-int pad
    int*            srcs  = (int*)alloc((size_t)N_NODES * CAP * 4);   // 19.2 MB
    unsigned short* h     = (unsigned short*)alloc((size_t)N_NODES * 64 * 2);  // fp16, 12.8 MB
    float*          g     = (float*)alloc((size_t)N_NODES * 64 * 4);  // 25.6 MB
    float*          als   = (float*)alloc((size_t)N_NODES * 4 * 4);
    float*          ald   = (float*)alloc((size_t)N_NODES * 4 * 4);
    // staging (12.85 MB) aliases g: consumed by bucket_fill before agg_h4 first writes g.
    unsigned*       stage = (unsigned*)g;

    hipMemsetAsync(tails, 0, (size_t)1024 * 4, stream);   // cnt memset not needed

    int g64  = G64;                    // 1563 (layers 1-2: NPB=64)
    int g128 = (N_NODES + 127) / 128;  // 782  (layer 3:   NPB=128)
    int gAgg = ((N_NODES + 3) / 4 + 7) & ~7;   // 25000 -> mult of 8

    // layer 1 gemm || bucket build (independent: x/W1 vs ei) in one dispatch
    gemm1_build<<<G64 + GBUILD, 256, 0, stream>>>(x, W1, as1, ad1, h, als, ald, ei, tails, stage);
    bucket_fill<<<NBIN, 1024, 0, stream>>>(tails, stage, cnt, srcs);

    agg_h4<<<gAgg, 256, 0, stream>>>(cnt, srcs, h, als, ald, b1, g, 1);
    // layer 2: g[100000,64] @ W2[64,64], H=4
    gemm_al<64, 64, 4><<<g64, 256, 0, stream>>>(g, W2, as2, ad2, h, als, ald);
    agg_h4<<<gAgg, 256, 0, stream>>>(cnt, srcs, h, als, ald, b2, g, 1);
    // layer 3: g[100000,64] @ W3[64,32], H=1 -> d_out
    gemm_al<64, 32, 1><<<g128, 256, 0, stream>>>(g, W3, as3, ad3, h, als, ald);
    agg_h1<<<gAgg, 256, 0, stream>>>(cnt, srcs, h, als, ald, b3, out);
}